// Round 1
// baseline (40980.307 us; speedup 1.0000x reference)
//
#include <hip/hip_runtime.h>
#include <math.h>

#define DD 128

// ---------------- zero fill (float4 grid-stride) ----------------
__global__ __launch_bounds__(256) void zero_f4(float4* __restrict__ p, long n4) {
    long i = (long)blockIdx.x * blockDim.x + threadIdx.x;
    long stride = (long)gridDim.x * blockDim.x;
    float4 z = {0.f, 0.f, 0.f, 0.f};
    for (; i < n4; i += stride) p[i] = z;
}

// ---------------- elementwise multiply in place: a *= b ----------------
__global__ __launch_bounds__(256) void mul_f4(float4* __restrict__ a,
                                              const float4* __restrict__ b, long n4) {
    long i = (long)blockIdx.x * blockDim.x + threadIdx.x;
    long stride = (long)gridDim.x * blockDim.x;
    for (; i < n4; i += stride) {
        float4 x = a[i], y = b[i];
        x.x *= y.x; x.y *= y.y; x.z *= y.z; x.w *= y.w;
        a[i] = x;
    }
}

// ---------------- edge scatter-add: agg[dst] += m[src] ----------------
__global__ __launch_bounds__(256) void scatter_add(const float* __restrict__ m,
                                                   const int* __restrict__ ei,
                                                   float* __restrict__ agg, int E) {
    int e = blockIdx.x * 2 + (threadIdx.x >> 7);
    if (e >= E) return;
    int c = threadIdx.x & 127;
    int s = ei[e];        // src = edge_index[0][e]
    int d = ei[E + e];    // dst = edge_index[1][e]
    atomicAdd(agg + (size_t)d * DD + c, m[(size_t)s * DD + c]);
}

// ---------------- GEMM: C = act(A1@W1(^T) [+ A2@W2^T] + b1 + b2) ----------------
// Block tile 128 rows x 128 cols, 256 threads, 8x8 micro-tile.
// W staged in LDS as float4 with XOR swizzle j = k4 ^ (c&31): 64KB static,
// 16-simultaneous-col ds_read_b128 -> 2-way bank conflict (free).
// A read direct from global (block-private rows, L1 broadcast).
// ACT: 0 none, 1 sigmoid, 2 GRU-final (v = i_n; reads rhn, z, h_prev).
// trans1: W1 stored [k][c] (W_msg); otherwise weights are [c_out][k].
template <int ACT, bool DUAL>
__global__ __launch_bounds__(256) void gemm128(
    const float* __restrict__ A1, const float* __restrict__ W1, int trans1,
    const float* __restrict__ A2, const float* __restrict__ W2,
    const float* __restrict__ b1, const float* __restrict__ b2,
    float* __restrict__ C, int M,
    const float* __restrict__ rhn_p, const float* __restrict__ z_p,
    const float* __restrict__ h_p)
{
    __shared__ float4 Wl[DD * 32];  // [c][j], j = k4 ^ (c&31)
    const int tid = threadIdx.x;
    const int rgrp = tid >> 4;  // 0..15
    const int cgrp = tid & 15;  // 0..15
    const int row0 = blockIdx.x * DD;

    float acc[8][8];
#pragma unroll
    for (int i = 0; i < 8; ++i)
#pragma unroll
        for (int j = 0; j < 8; ++j) acc[i][j] = 0.f;

#pragma unroll
    for (int ph = 0; ph < (DUAL ? 2 : 1); ++ph) {
        const float* A = (ph == 0) ? A1 : A2;
        const float* W = (ph == 0) ? W1 : W2;
        const int trans = (ph == 0) ? trans1 : 0;

        // ---- stage W into LDS (swizzled) ----
        if (!trans) {
            const float4* W4 = reinterpret_cast<const float4*>(W);
#pragma unroll
            for (int it = 0; it < 16; ++it) {
                int i4 = tid + it * 256;       // linear float4 index: c*32 + k4
                int c = i4 >> 5, k4 = i4 & 31;
                Wl[c * 32 + (k4 ^ (c & 31))] = W4[i4];
            }
        } else {
            float* Wls = reinterpret_cast<float*>(Wl);
            for (int it = 0; it < 64; ++it) {
                int idx = tid + it * 256;      // c fastest -> coalesced source read
                int c = idx & 127, k = idx >> 7;
                Wls[c * DD + ((k >> 2) ^ (c & 31)) * 4 + (k & 3)] = W[k * DD + c];
            }
        }
        __syncthreads();

        // ---- K loop ----
        const float4* Ar[8];
#pragma unroll
        for (int rr = 0; rr < 8; ++rr) {
            int r = row0 + rgrp + 16 * rr;
            if (r >= M) r = M - 1;
            Ar[rr] = reinterpret_cast<const float4*>(A + (size_t)r * DD);
        }
#pragma unroll
        for (int k4 = 0; k4 < 32; ++k4) {
            float4 a[8], w[8];
#pragma unroll
            for (int rr = 0; rr < 8; ++rr) a[rr] = Ar[rr][k4];
#pragma unroll
            for (int cc = 0; cc < 8; ++cc) {
                int c = cgrp + 16 * cc;
                w[cc] = Wl[c * 32 + (k4 ^ (c & 31))];
            }
#pragma unroll
            for (int rr = 0; rr < 8; ++rr)
#pragma unroll
                for (int cc = 0; cc < 8; ++cc) {
                    acc[rr][cc] += a[rr].x * w[cc].x;
                    acc[rr][cc] += a[rr].y * w[cc].y;
                    acc[rr][cc] += a[rr].z * w[cc].z;
                    acc[rr][cc] += a[rr].w * w[cc].w;
                }
        }
        __syncthreads();  // protects Wl re-staging AND in-place (ACT==2) stores
    }

    // ---- epilogue ----
#pragma unroll
    for (int rr = 0; rr < 8; ++rr) {
        int r = row0 + rgrp + 16 * rr;
        if (r >= M) continue;
#pragma unroll
        for (int cc = 0; cc < 8; ++cc) {
            int c = cgrp + 16 * cc;
            float v = acc[rr][cc];
            if (b1) v += b1[c];
            if (b2) v += b2[c];
            size_t idx = (size_t)r * DD + c;
            if (ACT == 1) {
                v = 1.f / (1.f + __expf(-v));
            } else if (ACT == 2) {
                float n = tanhf(v + rhn_p[idx]);
                float zv = z_p[idx];
                v = (1.f - zv) * n + zv * h_p[idx];
            }
            C[idx] = v;
        }
    }
}

extern "C" void kernel_launch(void* const* d_in, const int* in_sizes, int n_in,
                              void* d_out, int out_size, void* d_ws, size_t ws_size,
                              hipStream_t stream) {
    const float* x     = (const float*)d_in[0];
    const int*   ei    = (const int*)d_in[1];
    const float* W_in  = (const float*)d_in[2];
    const float* b_in  = (const float*)d_in[3];
    const float* W_msg = (const float*)d_in[4];
    const float* W_ih  = (const float*)d_in[5];
    const float* b_ih  = (const float*)d_in[6];
    const float* W_hh  = (const float*)d_in[7];
    const float* b_hh  = (const float*)d_in[8];
    const float* W_out = (const float*)d_in[9];
    const float* b_out = (const float*)d_in[10];

    const int N = in_sizes[0] / DD;     // 100000
    const int E = in_sizes[1] / 2;      // 1600000
    float* out = (float*)d_out;

    const size_t slot = (size_t)N * DD;
    // ws layout (3 slots): 0: h | 1: m -> hn -> z | 2: agg -> h_new
    float* h    = (float*)d_ws;
    float* s1   = h + slot;     // m, then hn, then z
    float* agg  = s1 + slot;    // agg, then h_new (in-place in K7)
    float* r    = out;          // d_out doubles as scratch for r, then r*hn

    dim3 blk(256);
    const int gblocks = (N + DD - 1) / DD;
    const long n4 = (long)(slot / 4);

    // K1: h = x @ W_in^T + b_in
    gemm128<0, false><<<gblocks, blk, 0, stream>>>(x, W_in, 0, nullptr, nullptr,
        b_in, nullptr, h, N, nullptr, nullptr, nullptr);
    // K3: zero agg
    zero_f4<<<2048, blk, 0, stream>>>((float4*)agg, n4);
    // K2: m = h @ W_msg   (W_msg is [k][c] -> transposed staging)
    gemm128<0, false><<<gblocks, blk, 0, stream>>>(h, W_msg, 1, nullptr, nullptr,
        nullptr, nullptr, s1, N, nullptr, nullptr, nullptr);
    // K4: agg[dst] += m[src]
    scatter_add<<<(E + 1) / 2, blk, 0, stream>>>(s1, ei, agg, E);
    // K5: r = sigmoid(agg@Wr^T + h@Ur^T + b_ih_r + b_hh_r)  -> d_out
    gemm128<1, true><<<gblocks, blk, 0, stream>>>(agg, W_ih, 0, h, W_hh,
        b_ih, b_hh, r, N, nullptr, nullptr, nullptr);
    // K5b: hn = h@Un^T + b_hh_n -> s1 (m dead)
    gemm128<0, false><<<gblocks, blk, 0, stream>>>(h, W_hh + 2 * DD * DD, 0, nullptr, nullptr,
        b_hh + 2 * DD, nullptr, s1, N, nullptr, nullptr, nullptr);
    // K_mul: r *= hn  (in d_out)
    mul_f4<<<2048, blk, 0, stream>>>((float4*)r, (const float4*)s1, n4);
    // K6: z = sigmoid(agg@Wz^T + h@Uz^T + b_ih_z + b_hh_z) -> s1 (hn dead)
    gemm128<1, true><<<gblocks, blk, 0, stream>>>(agg, W_ih + DD * DD, 0, h, W_hh + DD * DD,
        b_ih + DD, b_hh + DD, s1, N, nullptr, nullptr, nullptr);
    // K7: h_new = (1-z)*tanh(agg@Wn^T + b_ih_n + r*hn) + z*h -> agg slot (in place)
    gemm128<2, false><<<gblocks, blk, 0, stream>>>(agg, W_ih + 2 * DD * DD, 0, nullptr, nullptr,
        b_ih + 2 * DD, nullptr, agg, N, r, s1, h);
    // K8: out = h_new @ W_out^T + b_out -> d_out (r dead)
    gemm128<0, false><<<gblocks, blk, 0, stream>>>(agg, W_out, 0, nullptr, nullptr,
        b_out, nullptr, out, N, nullptr, nullptr, nullptr);
}

// Round 2
// 1481.645 us; speedup vs baseline: 27.6587x; 27.6587x over previous
//
#include <hip/hip_runtime.h>
#include <math.h>

#define DD 128

// ---------------- zero fill (float4 grid-stride) ----------------
__global__ __launch_bounds__(256) void zero_f4(float4* __restrict__ p, long n4) {
    long i = (long)blockIdx.x * blockDim.x + threadIdx.x;
    long stride = (long)gridDim.x * blockDim.x;
    float4 z = {0.f, 0.f, 0.f, 0.f};
    for (; i < n4; i += stride) p[i] = z;
}

// ---------------- elementwise multiply in place: a *= b ----------------
__global__ __launch_bounds__(256) void mul_f4(float4* __restrict__ a,
                                              const float4* __restrict__ b, long n4) {
    long i = (long)blockIdx.x * blockDim.x + threadIdx.x;
    long stride = (long)gridDim.x * blockDim.x;
    for (; i < n4; i += stride) {
        float4 x = a[i], y = b[i];
        x.x *= y.x; x.y *= y.y; x.z *= y.z; x.w *= y.w;
        a[i] = x;
    }
}

// ---------------- edge scatter-add: agg[dst] += m[src] ----------------
__global__ __launch_bounds__(256) void scatter_add(const float* __restrict__ m,
                                                   const int* __restrict__ ei,
                                                   float* __restrict__ agg, int E) {
    int e = blockIdx.x * 2 + (threadIdx.x >> 7);
    if (e >= E) return;
    int c = threadIdx.x & 127;
    int s = ei[e];        // src = edge_index[0][e]
    int d = ei[E + e];    // dst = edge_index[1][e]
    atomicAdd(agg + (size_t)d * DD + c, m[(size_t)s * DD + c]);
}

// ---------------- GEMM: C = act(A1@W1(^T) [+ A2@W2^T] + b1 + b2) ----------------
// Block tile 128 rows x 128 cols, 256 threads, 8x8 micro-tile.
// W staged in LDS as float4 with XOR swizzle j = k4 ^ (c&31): 64KB static,
// 2 blocks/CU. A read direct from global (block-private rows, L1 broadcast).
//
// R1 fix: k4 loop capped at `#pragma unroll 2` and only ONE w-float4 live at a
// time (load w per cc, then 8 FMAs) -> live regs ~140, no scratch spill.
// (R0 fully unrolled k4=32, hoisted 256 float4 loads, hit the 256-VGPR cap and
// spilled acc to scratch: 12.8 GB HBM traffic per dispatch.)
//
// ACT: 0 none, 1 sigmoid, 2 GRU-final (v = i_n; reads rhn, z, h_prev).
// trans1: W1 stored [k][c] (W_msg); otherwise weights are [c_out][k].
template <int ACT, bool DUAL>
__global__ __launch_bounds__(256) void gemm128(
    const float* __restrict__ A1, const float* __restrict__ W1, int trans1,
    const float* __restrict__ A2, const float* __restrict__ W2,
    const float* __restrict__ b1, const float* __restrict__ b2,
    float* __restrict__ C, int M,
    const float* __restrict__ rhn_p, const float* __restrict__ z_p,
    const float* __restrict__ h_p)
{
    __shared__ float4 Wl[DD * 32];  // [c][j], j = k4 ^ (c&31)
    const int tid = threadIdx.x;
    const int rgrp = tid >> 4;  // 0..15
    const int cgrp = tid & 15;  // 0..15
    const int row0 = blockIdx.x * DD;

    float acc[8][8];
#pragma unroll
    for (int i = 0; i < 8; ++i)
#pragma unroll
        for (int j = 0; j < 8; ++j) acc[i][j] = 0.f;

#pragma unroll 1
    for (int ph = 0; ph < (DUAL ? 2 : 1); ++ph) {
        const float* A = (ph == 0) ? A1 : A2;
        const float* W = (ph == 0) ? W1 : W2;
        const int trans = (ph == 0) ? trans1 : 0;

        // ---- stage W into LDS (swizzled) ----
        if (!trans) {
            const float4* W4 = reinterpret_cast<const float4*>(W);
#pragma unroll
            for (int it = 0; it < 16; ++it) {
                int i4 = tid + it * 256;       // linear float4 index: c*32 + k4
                int c = i4 >> 5, k4 = i4 & 31;
                Wl[c * 32 + (k4 ^ (c & 31))] = W4[i4];
            }
        } else {
            float* Wls = reinterpret_cast<float*>(Wl);
#pragma unroll 4
            for (int it = 0; it < 64; ++it) {
                int idx = tid + it * 256;      // c fastest -> coalesced source read
                int c = idx & 127, k = idx >> 7;
                Wls[c * DD + ((k >> 2) ^ (c & 31)) * 4 + (k & 3)] = W[k * DD + c];
            }
        }
        __syncthreads();

        // ---- K loop ----
        const float4* Ar[8];
#pragma unroll
        for (int rr = 0; rr < 8; ++rr) {
            int r = row0 + rgrp + 16 * rr;
            if (r >= M) r = M - 1;
            Ar[rr] = reinterpret_cast<const float4*>(A + (size_t)r * DD);
        }
#pragma unroll 2
        for (int k4 = 0; k4 < 32; ++k4) {
            float4 a[8];
#pragma unroll
            for (int rr = 0; rr < 8; ++rr) a[rr] = Ar[rr][k4];
#pragma unroll
            for (int cc = 0; cc < 8; ++cc) {
                const int c = cgrp + 16 * cc;
                const float4 w = Wl[c * 32 + (k4 ^ (c & 31))];
#pragma unroll
                for (int rr = 0; rr < 8; ++rr) {
                    acc[rr][cc] += a[rr].x * w.x;
                    acc[rr][cc] += a[rr].y * w.y;
                    acc[rr][cc] += a[rr].z * w.z;
                    acc[rr][cc] += a[rr].w * w.w;
                }
            }
        }
        __syncthreads();  // protects Wl re-staging AND in-place (ACT==2) stores
    }

    // ---- epilogue ----
#pragma unroll
    for (int rr = 0; rr < 8; ++rr) {
        int r = row0 + rgrp + 16 * rr;
        if (r >= M) continue;
#pragma unroll
        for (int cc = 0; cc < 8; ++cc) {
            int c = cgrp + 16 * cc;
            float v = acc[rr][cc];
            if (b1) v += b1[c];
            if (b2) v += b2[c];
            size_t idx = (size_t)r * DD + c;
            if (ACT == 1) {
                v = 1.f / (1.f + __expf(-v));
            } else if (ACT == 2) {
                float n = tanhf(v + rhn_p[idx]);
                float zv = z_p[idx];
                v = (1.f - zv) * n + zv * h_p[idx];
            }
            C[idx] = v;
        }
    }
}

extern "C" void kernel_launch(void* const* d_in, const int* in_sizes, int n_in,
                              void* d_out, int out_size, void* d_ws, size_t ws_size,
                              hipStream_t stream) {
    const float* x     = (const float*)d_in[0];
    const int*   ei    = (const int*)d_in[1];
    const float* W_in  = (const float*)d_in[2];
    const float* b_in  = (const float*)d_in[3];
    const float* W_msg = (const float*)d_in[4];
    const float* W_ih  = (const float*)d_in[5];
    const float* b_ih  = (const float*)d_in[6];
    const float* W_hh  = (const float*)d_in[7];
    const float* b_hh  = (const float*)d_in[8];
    const float* W_out = (const float*)d_in[9];
    const float* b_out = (const float*)d_in[10];

    const int N = in_sizes[0] / DD;     // 100000
    const int E = in_sizes[1] / 2;      // 1600000
    float* out = (float*)d_out;

    const size_t slot = (size_t)N * DD;
    // ws layout (3 slots): 0: h | 1: m -> hn -> z | 2: agg -> h_new
    float* h    = (float*)d_ws;
    float* s1   = h + slot;     // m, then hn, then z
    float* agg  = s1 + slot;    // agg, then h_new (in-place in K7)
    float* r    = out;          // d_out doubles as scratch for r, then r*hn

    dim3 blk(256);
    const int gblocks = (N + DD - 1) / DD;
    const long n4 = (long)(slot / 4);

    // K1: h = x @ W_in^T + b_in
    gemm128<0, false><<<gblocks, blk, 0, stream>>>(x, W_in, 0, nullptr, nullptr,
        b_in, nullptr, h, N, nullptr, nullptr, nullptr);
    // K3: zero agg
    zero_f4<<<2048, blk, 0, stream>>>((float4*)agg, n4);
    // K2: m = h @ W_msg   (W_msg is [k][c] -> transposed staging)
    gemm128<0, false><<<gblocks, blk, 0, stream>>>(h, W_msg, 1, nullptr, nullptr,
        nullptr, nullptr, s1, N, nullptr, nullptr, nullptr);
    // K4: agg[dst] += m[src]
    scatter_add<<<(E + 1) / 2, blk, 0, stream>>>(s1, ei, agg, E);
    // K5: r = sigmoid(agg@Wr^T + h@Ur^T + b_ih_r + b_hh_r)  -> d_out
    gemm128<1, true><<<gblocks, blk, 0, stream>>>(agg, W_ih, 0, h, W_hh,
        b_ih, b_hh, r, N, nullptr, nullptr, nullptr);
    // K5b: hn = h@Un^T + b_hh_n -> s1 (m dead)
    gemm128<0, false><<<gblocks, blk, 0, stream>>>(h, W_hh + 2 * DD * DD, 0, nullptr, nullptr,
        b_hh + 2 * DD, nullptr, s1, N, nullptr, nullptr, nullptr);
    // K_mul: r *= hn  (in d_out)
    mul_f4<<<2048, blk, 0, stream>>>((float4*)r, (const float4*)s1, n4);
    // K6: z = sigmoid(agg@Wz^T + h@Uz^T + b_ih_z + b_hh_z) -> s1 (hn dead)
    gemm128<1, true><<<gblocks, blk, 0, stream>>>(agg, W_ih + DD * DD, 0, h, W_hh + DD * DD,
        b_ih + DD, b_hh + DD, s1, N, nullptr, nullptr, nullptr);
    // K7: h_new = (1-z)*tanh(agg@Wn^T + b_ih_n + r*hn) + z*h -> agg slot (in place)
    gemm128<2, false><<<gblocks, blk, 0, stream>>>(agg, W_ih + 2 * DD * DD, 0, nullptr, nullptr,
        b_ih + 2 * DD, nullptr, agg, N, r, s1, h);
    // K8: out = h_new @ W_out^T + b_out -> d_out (r dead)
    gemm128<0, false><<<gblocks, blk, 0, stream>>>(agg, W_out, 0, nullptr, nullptr,
        b_out, nullptr, out, N, nullptr, nullptr, nullptr);
}

// Round 3
// 1103.164 us; speedup vs baseline: 37.1480x; 1.3431x over previous
//
#include <hip/hip_runtime.h>
#include <math.h>

#define DD 128

// ---------------- zero fill (float4 grid-stride) ----------------
__global__ __launch_bounds__(256) void zero_f4(float4* __restrict__ p, long n4) {
    long i = (long)blockIdx.x * blockDim.x + threadIdx.x;
    long stride = (long)gridDim.x * blockDim.x;
    float4 z = {0.f, 0.f, 0.f, 0.f};
    for (; i < n4; i += stride) p[i] = z;
}

// ---------------- elementwise multiply in place: a *= b ----------------
__global__ __launch_bounds__(256) void mul_f4(float4* __restrict__ a,
                                              const float4* __restrict__ b, long n4) {
    long i = (long)blockIdx.x * blockDim.x + threadIdx.x;
    long stride = (long)gridDim.x * blockDim.x;
    for (; i < n4; i += stride) {
        float4 x = a[i], y = b[i];
        x.x *= y.x; x.y *= y.y; x.z *= y.z; x.w *= y.w;
        a[i] = x;
    }
}

// ================= CSR build (by dst) + gather-sum aggregation =============
// Replaces 204.8M f32 atomicAdds (R1: 819 MB HBM write, 680 us) with
// 3.2M int atomics + one coalesced gather-sum pass over L3-resident m.

// count[dst]++ per edge
__global__ __launch_bounds__(256) void hist_dst(const int* __restrict__ ei,
                                                int* __restrict__ cnt, int E) {
    int e = blockIdx.x * 256 + threadIdx.x;
    if (e < E) atomicAdd(&cnt[ei[E + e]], 1);
}

// block-local exclusive scan: 256 threads x 4 nodes = 1024 nodes/block
__global__ __launch_bounds__(256) void scanA(const int* __restrict__ cnt,
                                             int* __restrict__ off,
                                             int* __restrict__ bsum, int N) {
    __shared__ int sdata[256];
    const int t = threadIdx.x;
    const int v0 = blockIdx.x * 1024 + t * 4;
    int l0 = (v0 + 0 < N) ? cnt[v0 + 0] : 0;
    int l1 = (v0 + 1 < N) ? cnt[v0 + 1] : 0;
    int l2 = (v0 + 2 < N) ? cnt[v0 + 2] : 0;
    int l3 = (v0 + 3 < N) ? cnt[v0 + 3] : 0;
    int s = l0 + l1 + l2 + l3;
    sdata[t] = s;
    __syncthreads();
    for (int o = 1; o < 256; o <<= 1) {
        int v = (t >= o) ? sdata[t - o] : 0;
        __syncthreads();
        sdata[t] += v;
        __syncthreads();
    }
    int excl = sdata[t] - s;  // exclusive within block
    if (v0 + 0 < N) off[v0 + 0] = excl;
    if (v0 + 1 < N) off[v0 + 1] = excl + l0;
    if (v0 + 2 < N) off[v0 + 2] = excl + l0 + l1;
    if (v0 + 3 < N) off[v0 + 3] = excl + l0 + l1 + l2;
    if (t == 255) bsum[blockIdx.x] = sdata[255];
}

// exclusive scan of NB block sums (NB <= 128), single block
__global__ __launch_bounds__(128) void scanB(const int* __restrict__ bsum,
                                             int* __restrict__ bbase, int NB) {
    __shared__ int sdata[128];
    const int t = threadIdx.x;
    int s = (t < NB) ? bsum[t] : 0;
    sdata[t] = s;
    __syncthreads();
    for (int o = 1; o < 128; o <<= 1) {
        int v = (t >= o) ? sdata[t - o] : 0;
        __syncthreads();
        sdata[t] += v;
        __syncthreads();
    }
    if (t < NB) bbase[t] = sdata[t] - s;
}

// off[v] += bbase[block]; cursor[v] = off[v]; off[N] = E
__global__ __launch_bounds__(256) void scanC(int* __restrict__ off,
                                             int* __restrict__ cursor,
                                             const int* __restrict__ bbase,
                                             int N, int E) {
    const int t = threadIdx.x;
    const int v0 = blockIdx.x * 1024 + t * 4;
    const int base = bbase[blockIdx.x];
#pragma unroll
    for (int j = 0; j < 4; ++j) {
        int v = v0 + j;
        if (v < N) {
            int o = off[v] + base;
            off[v] = o;
            cursor[v] = o;
        }
    }
    if (blockIdx.x == 0 && t == 0) off[N] = E;
}

// bucket[atomicAdd(cursor[dst])] = src
__global__ __launch_bounds__(256) void fill_bucket(const int* __restrict__ ei,
                                                   int* __restrict__ cursor,
                                                   int* __restrict__ bucket, int E) {
    int e = blockIdx.x * 256 + threadIdx.x;
    if (e < E) {
        int d = ei[E + e];
        int pos = atomicAdd(&cursor[d], 1);
        bucket[pos] = ei[e];  // src
    }
}

// agg[v][c] = sum_{i in [off[v],off[v+1])} m[bucket[i]][c]
// one block (128 threads) per node; coalesced 512B row reads, L3-resident m.
__global__ __launch_bounds__(128) void gather_sum(const float* __restrict__ m,
                                                  const int* __restrict__ off,
                                                  const int* __restrict__ bucket,
                                                  float* __restrict__ agg, int N) {
    const int v = blockIdx.x;
    const int c = threadIdx.x;
    const int start = off[v], end = off[v + 1];
    float s = 0.f;
    int i = start;
    for (; i + 4 <= end; i += 4) {
        int i0 = bucket[i], i1 = bucket[i + 1], i2 = bucket[i + 2], i3 = bucket[i + 3];
        float a0 = m[(size_t)i0 * DD + c];
        float a1 = m[(size_t)i1 * DD + c];
        float a2 = m[(size_t)i2 * DD + c];
        float a3 = m[(size_t)i3 * DD + c];
        s += a0 + a1 + a2 + a3;
    }
    for (; i < end; ++i) s += m[(size_t)bucket[i] * DD + c];
    agg[(size_t)v * DD + c] = s;
}

// ---------------- GEMM: C = act(A1@W1(^T) [+ A2@W2^T] + b1 + b2) ----------------
// Block tile 128 rows x 128 cols, 256 threads, 8x8 micro-tile.
// W staged in LDS as float4 with XOR swizzle j = k4 ^ (c&31): 64KB static,
// 2 blocks/CU. A read direct from global (block-private rows, L1 broadcast).
// k4 loop `#pragma unroll 2`, one w-float4 live at a time -> no spill (R1 fix).
// ACT: 0 none, 1 sigmoid, 2 GRU-final (v = i_n; reads rhn, z, h_prev).
// trans1: W1 stored [k][c] (W_msg); otherwise weights are [c_out][k].
template <int ACT, bool DUAL>
__global__ __launch_bounds__(256) void gemm128(
    const float* __restrict__ A1, const float* __restrict__ W1, int trans1,
    const float* __restrict__ A2, const float* __restrict__ W2,
    const float* __restrict__ b1, const float* __restrict__ b2,
    float* __restrict__ C, int M,
    const float* __restrict__ rhn_p, const float* __restrict__ z_p,
    const float* __restrict__ h_p)
{
    __shared__ float4 Wl[DD * 32];  // [c][j], j = k4 ^ (c&31)
    const int tid = threadIdx.x;
    const int rgrp = tid >> 4;  // 0..15
    const int cgrp = tid & 15;  // 0..15
    const int row0 = blockIdx.x * DD;

    float acc[8][8];
#pragma unroll
    for (int i = 0; i < 8; ++i)
#pragma unroll
        for (int j = 0; j < 8; ++j) acc[i][j] = 0.f;

#pragma unroll 1
    for (int ph = 0; ph < (DUAL ? 2 : 1); ++ph) {
        const float* A = (ph == 0) ? A1 : A2;
        const float* W = (ph == 0) ? W1 : W2;
        const int trans = (ph == 0) ? trans1 : 0;

        // ---- stage W into LDS (swizzled) ----
        if (!trans) {
            const float4* W4 = reinterpret_cast<const float4*>(W);
#pragma unroll
            for (int it = 0; it < 16; ++it) {
                int i4 = tid + it * 256;       // linear float4 index: c*32 + k4
                int c = i4 >> 5, k4 = i4 & 31;
                Wl[c * 32 + (k4 ^ (c & 31))] = W4[i4];
            }
        } else {
            float* Wls = reinterpret_cast<float*>(Wl);
#pragma unroll 4
            for (int it = 0; it < 64; ++it) {
                int idx = tid + it * 256;      // c fastest -> coalesced source read
                int c = idx & 127, k = idx >> 7;
                Wls[c * DD + ((k >> 2) ^ (c & 31)) * 4 + (k & 3)] = W[k * DD + c];
            }
        }
        __syncthreads();

        // ---- K loop ----
        const float4* Ar[8];
#pragma unroll
        for (int rr = 0; rr < 8; ++rr) {
            int r = row0 + rgrp + 16 * rr;
            if (r >= M) r = M - 1;
            Ar[rr] = reinterpret_cast<const float4*>(A + (size_t)r * DD);
        }
#pragma unroll 2
        for (int k4 = 0; k4 < 32; ++k4) {
            float4 a[8];
#pragma unroll
            for (int rr = 0; rr < 8; ++rr) a[rr] = Ar[rr][k4];
#pragma unroll
            for (int cc = 0; cc < 8; ++cc) {
                const int c = cgrp + 16 * cc;
                const float4 w = Wl[c * 32 + (k4 ^ (c & 31))];
#pragma unroll
                for (int rr = 0; rr < 8; ++rr) {
                    acc[rr][cc] += a[rr].x * w.x;
                    acc[rr][cc] += a[rr].y * w.y;
                    acc[rr][cc] += a[rr].z * w.z;
                    acc[rr][cc] += a[rr].w * w.w;
                }
            }
        }
        __syncthreads();  // protects Wl re-staging AND in-place (ACT==2) stores
    }

    // ---- epilogue ----
#pragma unroll
    for (int rr = 0; rr < 8; ++rr) {
        int r = row0 + rgrp + 16 * rr;
        if (r >= M) continue;
#pragma unroll
        for (int cc = 0; cc < 8; ++cc) {
            int c = cgrp + 16 * cc;
            float v = acc[rr][cc];
            if (b1) v += b1[c];
            if (b2) v += b2[c];
            size_t idx = (size_t)r * DD + c;
            if (ACT == 1) {
                v = 1.f / (1.f + __expf(-v));
            } else if (ACT == 2) {
                float n = tanhf(v + rhn_p[idx]);
                float zv = z_p[idx];
                v = (1.f - zv) * n + zv * h_p[idx];
            }
            C[idx] = v;
        }
    }
}

extern "C" void kernel_launch(void* const* d_in, const int* in_sizes, int n_in,
                              void* d_out, int out_size, void* d_ws, size_t ws_size,
                              hipStream_t stream) {
    const float* x     = (const float*)d_in[0];
    const int*   ei    = (const int*)d_in[1];
    const float* W_in  = (const float*)d_in[2];
    const float* b_in  = (const float*)d_in[3];
    const float* W_msg = (const float*)d_in[4];
    const float* W_ih  = (const float*)d_in[5];
    const float* b_ih  = (const float*)d_in[6];
    const float* W_hh  = (const float*)d_in[7];
    const float* b_hh  = (const float*)d_in[8];
    const float* W_out = (const float*)d_in[9];
    const float* b_out = (const float*)d_in[10];

    const int N = in_sizes[0] / DD;     // 100000
    const int E = in_sizes[1] / 2;      // 1600000
    float* out = (float*)d_out;

    const size_t slot = (size_t)N * DD;
    // ws layout (3 slots): 0: h | 1: m -> hn -> z | 2: agg -> h_new
    float* h    = (float*)d_ws;
    float* s1   = h + slot;     // m, then hn, then z
    float* agg  = s1 + slot;    // agg, then h_new (in-place in K7)
    float* r    = out;          // d_out doubles as scratch for r, then r*hn

    // CSR scratch lives in d_out (dead until K5): 7.2 MB of ints << 51.2 MB
    const int NB = (N + 1023) / 1024;   // 98 scan blocks
    int* cnt    = (int*)d_out;          // counts, then cursor
    int* off    = cnt + N;              // N+1 offsets
    int* bucket = off + N + 1;          // E src indices, grouped by dst
    int* bsum   = bucket + E;           // NB block sums
    int* bbase  = bsum + NB;            // NB block bases

    dim3 blk(256);
    const int gblocks = (N + DD - 1) / DD;
    const long n4 = (long)(slot / 4);

    // K1: h = x @ W_in^T + b_in
    gemm128<0, false><<<gblocks, blk, 0, stream>>>(x, W_in, 0, nullptr, nullptr,
        b_in, nullptr, h, N, nullptr, nullptr, nullptr);
    // K2: m = h @ W_msg   (W_msg is [k][c] -> transposed staging)
    gemm128<0, false><<<gblocks, blk, 0, stream>>>(h, W_msg, 1, nullptr, nullptr,
        nullptr, nullptr, s1, N, nullptr, nullptr, nullptr);

    // ---- CSR build + aggregate: agg[v] = sum over in-edges of m[src] ----
    zero_f4<<<128, blk, 0, stream>>>((float4*)cnt, (long)(N / 4));
    hist_dst<<<(E + 255) / 256, blk, 0, stream>>>(ei, cnt, E);
    scanA<<<NB, blk, 0, stream>>>(cnt, off, bsum, N);
    scanB<<<1, 128, 0, stream>>>(bsum, bbase, NB);
    scanC<<<NB, blk, 0, stream>>>(off, cnt, bbase, N, E);
    fill_bucket<<<(E + 255) / 256, blk, 0, stream>>>(ei, cnt, bucket, E);
    gather_sum<<<N, 128, 0, stream>>>(s1, off, bucket, agg, N);

    // K5: r = sigmoid(agg@Wr^T + h@Ur^T + b_ih_r + b_hh_r)  -> d_out
    gemm128<1, true><<<gblocks, blk, 0, stream>>>(agg, W_ih, 0, h, W_hh,
        b_ih, b_hh, r, N, nullptr, nullptr, nullptr);
    // K5b: hn = h@Un^T + b_hh_n -> s1 (m dead)
    gemm128<0, false><<<gblocks, blk, 0, stream>>>(h, W_hh + 2 * DD * DD, 0, nullptr, nullptr,
        b_hh + 2 * DD, nullptr, s1, N, nullptr, nullptr, nullptr);
    // K_mul: r *= hn  (in d_out)
    mul_f4<<<2048, blk, 0, stream>>>((float4*)r, (const float4*)s1, n4);
    // K6: z = sigmoid(agg@Wz^T + h@Uz^T + b_ih_z + b_hh_z) -> s1 (hn dead)
    gemm128<1, true><<<gblocks, blk, 0, stream>>>(agg, W_ih + DD * DD, 0, h, W_hh + DD * DD,
        b_ih + DD, b_hh + DD, s1, N, nullptr, nullptr, nullptr);
    // K7: h_new = (1-z)*tanh(agg@Wn^T + b_ih_n + r*hn) + z*h -> agg slot (in place)
    gemm128<2, false><<<gblocks, blk, 0, stream>>>(agg, W_ih + 2 * DD * DD, 0, nullptr, nullptr,
        b_ih + 2 * DD, nullptr, agg, N, r, s1, h);
    // K8: out = h_new @ W_out^T + b_out -> d_out (r dead)
    gemm128<0, false><<<gblocks, blk, 0, stream>>>(agg, W_out, 0, nullptr, nullptr,
        b_out, nullptr, out, N, nullptr, nullptr, nullptr);
}

// Round 4
// 414.541 us; speedup vs baseline: 98.8570x; 2.6612x over previous
//
#include <hip/hip_runtime.h>
#include <math.h>

#define DD 128

using bf16x8 = __attribute__((ext_vector_type(8))) short;
using f32x4  = __attribute__((ext_vector_type(4))) float;

__device__ inline unsigned short f2bf(float f) {
    unsigned int u = __float_as_uint(f);
    unsigned int r = (u + 0x7fffu + ((u >> 16) & 1u)) >> 16;   // RNE
    return (unsigned short)r;
}
__device__ inline float bf2f(unsigned short h) {
    return __uint_as_float(((unsigned int)h) << 16);
}

#define MFMA16(a, b, c) __builtin_amdgcn_mfma_f32_16x16x32_bf16((a), (b), (c), 0, 0, 0)

// Stage a 128x128 bf16 weight matrix (row-major [n][k]) into LDS, 16B chunks
// XOR-swizzled: chunk ch of row n lands at n*16 + (ch ^ (n&15)).
__device__ inline void stageW(float4* lds, const unsigned short* W, int tid) {
    const float4* src = reinterpret_cast<const float4*>(W);
#pragma unroll
    for (int it = 0; it < 8; ++it) {
        int i = tid + it * 256;          // 0..2047 float4 chunks
        int n = i >> 4, ch = i & 15;
        lds[n * 16 + (ch ^ (n & 15))] = src[i];
    }
}

// Fragment read from a swizzled LDS matrix: row r, k-slice s, lane hi=(lane>>4).
// Returns 8 bf16 = row r, k = s*32 + 8*hi .. +7.
__device__ inline bf16x8 fragL(const float4* lds, int lane, int s, int r) {
    float4 v = lds[r * 16 + (((s << 2) + (lane >> 4)) ^ (r & 15))];
    return __builtin_bit_cast(bf16x8, v);
}

// A-fragment direct from global bf16 [.][128]: row, k-offset koff (16B aligned)
__device__ inline bf16x8 fragG(const unsigned short* A, long row, int koff) {
    float4 v = *reinterpret_cast<const float4*>(A + row * DD + koff);
    return __builtin_bit_cast(bf16x8, v);
}

// A-fragment from global fp32 [.][128] with convert
__device__ inline bf16x8 fragGF(const float* A, long row, int koff) {
    const float4* p = reinterpret_cast<const float4*>(A + row * DD + koff);
    float4 a = p[0], b = p[1];
    bf16x8 r;
    r[0] = f2bf(a.x); r[1] = f2bf(a.y); r[2] = f2bf(a.z); r[3] = f2bf(a.w);
    r[4] = f2bf(b.x); r[5] = f2bf(b.y); r[6] = f2bf(b.z); r[7] = f2bf(b.w);
    return r;
}

// ---------------- zero fill (float4 grid-stride) ----------------
__global__ __launch_bounds__(256) void zero_f4(float4* __restrict__ p, long n4) {
    long i = (long)blockIdx.x * blockDim.x + threadIdx.x;
    long stride = (long)gridDim.x * blockDim.x;
    float4 z = {0.f, 0.f, 0.f, 0.f};
    for (; i < n4; i += stride) p[i] = z;
}

// ---------------- weight convert to bf16 (+ W_msg transpose) ----------------
// wb layout (elements): [0) W_in 16384 | [16384) W_msgT 16384 | [32768) W_ih 49152
//                       | [81920) W_hh 49152 | [131072) W_out 16384  = 147456
__global__ __launch_bounds__(256) void wconv(
    const float* __restrict__ W_in, const float* __restrict__ W_msg,
    const float* __restrict__ W_ih, const float* __restrict__ W_hh,
    const float* __restrict__ W_out, unsigned short* __restrict__ wb)
{
    int i = blockIdx.x * 256 + threadIdx.x;
    if (i < 16384) wb[i] = f2bf(W_in[i]);
    else if (i < 32768) {
        int j = i - 16384; int n = j >> 7, k = j & 127;
        wb[i] = f2bf(W_msg[k * DD + n]);       // transpose: [n][k] = W_msg[k][n]
    }
    else if (i < 81920)  wb[i] = f2bf(W_ih[i - 32768]);
    else if (i < 131072) wb[i] = f2bf(W_hh[i - 81920]);
    else if (i < 147456) wb[i] = f2bf(W_out[i - 131072]);
}

// ================= CSR build (by dst) =============
__global__ __launch_bounds__(256) void hist_dst(const int* __restrict__ ei,
                                                int* __restrict__ cnt, int E) {
    int e = blockIdx.x * 256 + threadIdx.x;
    if (e < E) atomicAdd(&cnt[ei[E + e]], 1);
}

__global__ __launch_bounds__(256) void scanA(const int* __restrict__ cnt,
                                             int* __restrict__ off,
                                             int* __restrict__ bsum, int N) {
    __shared__ int sdata[256];
    const int t = threadIdx.x;
    const int v0 = blockIdx.x * 1024 + t * 4;
    int l0 = (v0 + 0 < N) ? cnt[v0 + 0] : 0;
    int l1 = (v0 + 1 < N) ? cnt[v0 + 1] : 0;
    int l2 = (v0 + 2 < N) ? cnt[v0 + 2] : 0;
    int l3 = (v0 + 3 < N) ? cnt[v0 + 3] : 0;
    int s = l0 + l1 + l2 + l3;
    sdata[t] = s;
    __syncthreads();
    for (int o = 1; o < 256; o <<= 1) {
        int v = (t >= o) ? sdata[t - o] : 0;
        __syncthreads();
        sdata[t] += v;
        __syncthreads();
    }
    int excl = sdata[t] - s;
    if (v0 + 0 < N) off[v0 + 0] = excl;
    if (v0 + 1 < N) off[v0 + 1] = excl + l0;
    if (v0 + 2 < N) off[v0 + 2] = excl + l0 + l1;
    if (v0 + 3 < N) off[v0 + 3] = excl + l0 + l1 + l2;
    if (t == 255) bsum[blockIdx.x] = sdata[255];
}

__global__ __launch_bounds__(128) void scanB(const int* __restrict__ bsum,
                                             int* __restrict__ bbase, int NB) {
    __shared__ int sdata[128];
    const int t = threadIdx.x;
    int s = (t < NB) ? bsum[t] : 0;
    sdata[t] = s;
    __syncthreads();
    for (int o = 1; o < 128; o <<= 1) {
        int v = (t >= o) ? sdata[t - o] : 0;
        __syncthreads();
        sdata[t] += v;
        __syncthreads();
    }
    if (t < NB) bbase[t] = sdata[t] - s;
}

__global__ __launch_bounds__(256) void scanC(int* __restrict__ off,
                                             int* __restrict__ cursor,
                                             const int* __restrict__ bbase,
                                             int N, int E) {
    const int t = threadIdx.x;
    const int v0 = blockIdx.x * 1024 + t * 4;
    const int base = bbase[blockIdx.x];
#pragma unroll
    for (int j = 0; j < 4; ++j) {
        int v = v0 + j;
        if (v < N) {
            int o = off[v] + base;
            off[v] = o;
            cursor[v] = o;
        }
    }
    if (blockIdx.x == 0 && t == 0) off[N] = E;
}

__global__ __launch_bounds__(256) void fill_bucket(const int* __restrict__ ei,
                                                   int* __restrict__ cursor,
                                                   int* __restrict__ bucket, int E) {
    int e = blockIdx.x * 256 + threadIdx.x;
    if (e < E) {
        int d = ei[E + e];
        int pos = atomicAdd(&cursor[d], 1);
        bucket[pos] = ei[e];
    }
}

// ---------------- gather-sum over bf16 m: one wave per node ----------------
__global__ __launch_bounds__(256) void gather_sum_bf(
    const unsigned short* __restrict__ m, const int* __restrict__ off,
    const int* __restrict__ bucket, unsigned short* __restrict__ agg, int N)
{
    const int v = blockIdx.x * 4 + (threadIdx.x >> 6);
    if (v >= N) return;
    const int lane = threadIdx.x & 63;
    const int start = off[v], end = off[v + 1];
    float s0 = 0.f, s1 = 0.f;
    int i = start;
    for (; i + 4 <= end; i += 4) {
        int i0 = bucket[i], i1 = bucket[i + 1], i2 = bucket[i + 2], i3 = bucket[i + 3];
        unsigned int a0 = *(const unsigned int*)(m + (size_t)i0 * DD + lane * 2);
        unsigned int a1 = *(const unsigned int*)(m + (size_t)i1 * DD + lane * 2);
        unsigned int a2 = *(const unsigned int*)(m + (size_t)i2 * DD + lane * 2);
        unsigned int a3 = *(const unsigned int*)(m + (size_t)i3 * DD + lane * 2);
        s0 += bf2f(a0 & 0xffff) + bf2f(a1 & 0xffff) + bf2f(a2 & 0xffff) + bf2f(a3 & 0xffff);
        s1 += bf2f(a0 >> 16) + bf2f(a1 >> 16) + bf2f(a2 >> 16) + bf2f(a3 >> 16);
    }
    for (; i < end; ++i) {
        unsigned int a = *(const unsigned int*)(m + (size_t)bucket[i] * DD + lane * 2);
        s0 += bf2f(a & 0xffff);
        s1 += bf2f(a >> 16);
    }
    unsigned int pk = ((unsigned int)f2bf(s1) << 16) | f2bf(s0);
    *(unsigned int*)(agg + (size_t)v * DD + lane * 2) = pk;
}

// ---------------- k12: h = x@W_in^T + b_in ; m = h@W_msg  (fused) ----------------
// Block = 64 rows, 4 waves x 16 rows. Phase 1 A from global fp32 x; h tile kept
// in LDS (overlaid on W_in slot after sync) as bf16 for phase 2. 64KB LDS.
__global__ __launch_bounds__(256) void k12(
    const float* __restrict__ x, const unsigned short* __restrict__ Wi,
    const unsigned short* __restrict__ Wm, const float* __restrict__ b_in,
    unsigned short* __restrict__ h_bf, unsigned short* __restrict__ m_bf, int M)
{
    __shared__ float4 WA[2048];   // W_in, then h tile (overlay)
    __shared__ float4 WB[2048];   // W_msgT
    const int tid = threadIdx.x;
    const int lane = tid & 63;
    const int w = tid >> 6;
    const int c15 = lane & 15;
    const int hi = lane >> 4;
    const long base = (long)blockIdx.x * 64;
    long arow = base + w * 16 + c15;
    if (arow >= M) arow = M - 1;

    stageW(WA, Wi, tid);
    stageW(WB, Wm, tid);
    __syncthreads();

    f32x4 acc[8];
#pragma unroll
    for (int ct = 0; ct < 8; ++ct) acc[ct] = (f32x4){0.f, 0.f, 0.f, 0.f};
#pragma unroll 1
    for (int s = 0; s < 4; ++s) {
        bf16x8 a = fragGF(x, arow, s * 32 + 8 * hi);
#pragma unroll
        for (int ct = 0; ct < 8; ++ct)
            acc[ct] = MFMA16(a, fragL(WB - 2048 + 2048, lane, s, 0), acc[ct]);  // placeholder
    }
    // NOTE: the line above is replaced below -- see real loop
    // (kept structure explicit; recompute properly:)
#pragma unroll
    for (int ct = 0; ct < 8; ++ct) acc[ct] = (f32x4){0.f, 0.f, 0.f, 0.f};
#pragma unroll 1
    for (int s = 0; s < 4; ++s) {
        bf16x8 a = fragGF(x, arow, s * 32 + 8 * hi);
#pragma unroll
        for (int ct = 0; ct < 8; ++ct)
            acc[ct] = MFMA16(a, fragL(WA, lane, s, ct * 16 + c15), acc[ct]);
    }
    __syncthreads();   // all waves done reading WA before overlay

    unsigned short* Hu = reinterpret_cast<unsigned short*>(WA);
#pragma unroll
    for (int ct = 0; ct < 8; ++ct)
#pragma unroll
        for (int j = 0; j < 4; ++j) {
            int rloc = w * 16 + 4 * hi + j;
            long r = base + rloc;
            int c = ct * 16 + c15;
            float v = acc[ct][j] + b_in[c];
            unsigned short hv = f2bf(v);
            Hu[rloc * DD + ((c >> 3) ^ (rloc & 15)) * 8 + (c & 7)] = hv;
            if (r < M) h_bf[r * DD + c] = hv;
        }
    __syncthreads();

    // phase 2: m = h @ W_msg  (A from LDS h tile, B = W_msgT)
#pragma unroll
    for (int ct = 0; ct < 8; ++ct) acc[ct] = (f32x4){0.f, 0.f, 0.f, 0.f};
#pragma unroll 1
    for (int s = 0; s < 4; ++s) {
        bf16x8 a = fragL(WA, lane, s, w * 16 + c15);
#pragma unroll
        for (int ct = 0; ct < 8; ++ct)
            acc[ct] = MFMA16(a, fragL(WB, lane, s, ct * 16 + c15), acc[ct]);
    }
#pragma unroll
    for (int ct = 0; ct < 8; ++ct)
#pragma unroll
        for (int j = 0; j < 4; ++j) {
            long r = base + w * 16 + 4 * hi + j;
            if (r < M) m_bf[r * DD + ct * 16 + c15] = f2bf(acc[ct][j]);
        }
}

// ---------------- gru8: gates + GRU + out = h_new@W_out^T + b_out ----------------
// Block = 64 rows. Per gate: stage W_ih_g, W_hh_g (64KB), dual-A MFMA.
// h_new -> LDS (overlay WA) -> final GEMM vs W_out (staged into WB). 64KB LDS.
__global__ __launch_bounds__(256) void gru8(
    const unsigned short* __restrict__ agg, const unsigned short* __restrict__ hbf,
    const unsigned short* __restrict__ Wih, const unsigned short* __restrict__ Whh,
    const unsigned short* __restrict__ Wo,
    const float* __restrict__ b_ih, const float* __restrict__ b_hh,
    const float* __restrict__ b_out, float* __restrict__ out, int M)
{
    __shared__ float4 WA[2048];
    __shared__ float4 WB[2048];
    const int tid = threadIdx.x;
    const int lane = tid & 63;
    const int w = tid >> 6;
    const int c15 = lane & 15;
    const int hi = lane >> 4;
    const long base = (long)blockIdx.x * 64;
    long arow = base + w * 16 + c15;
    if (arow >= M) arow = M - 1;

    f32x4 acc[8];
    float rg[32], zg[32];

    // ---- gate r ----
    stageW(WA, Wih, tid);
    stageW(WB, Whh, tid);
    __syncthreads();
#pragma unroll
    for (int ct = 0; ct < 8; ++ct) acc[ct] = (f32x4){0.f, 0.f, 0.f, 0.f};
#pragma unroll 1
    for (int s = 0; s < 4; ++s) {
        bf16x8 ai = fragG(agg, arow, s * 32 + 8 * hi);
        bf16x8 ah = fragG(hbf, arow, s * 32 + 8 * hi);
#pragma unroll
        for (int ct = 0; ct < 8; ++ct) {
            acc[ct] = MFMA16(ai, fragL(WA, lane, s, ct * 16 + c15), acc[ct]);
            acc[ct] = MFMA16(ah, fragL(WB, lane, s, ct * 16 + c15), acc[ct]);
        }
    }
#pragma unroll
    for (int ct = 0; ct < 8; ++ct)
#pragma unroll
        for (int j = 0; j < 4; ++j) {
            int c = ct * 16 + c15;
            float v = acc[ct][j] + b_ih[c] + b_hh[c];
            rg[ct * 4 + j] = 1.f / (1.f + __expf(-v));
        }
    __syncthreads();

    // ---- gate z ----
    stageW(WA, Wih + 16384, tid);
    stageW(WB, Whh + 16384, tid);
    __syncthreads();
#pragma unroll
    for (int ct = 0; ct < 8; ++ct) acc[ct] = (f32x4){0.f, 0.f, 0.f, 0.f};
#pragma unroll 1
    for (int s = 0; s < 4; ++s) {
        bf16x8 ai = fragG(agg, arow, s * 32 + 8 * hi);
        bf16x8 ah = fragG(hbf, arow, s * 32 + 8 * hi);
#pragma unroll
        for (int ct = 0; ct < 8; ++ct) {
            acc[ct] = MFMA16(ai, fragL(WA, lane, s, ct * 16 + c15), acc[ct]);
            acc[ct] = MFMA16(ah, fragL(WB, lane, s, ct * 16 + c15), acc[ct]);
        }
    }
#pragma unroll
    for (int ct = 0; ct < 8; ++ct)
#pragma unroll
        for (int j = 0; j < 4; ++j) {
            int c = ct * 16 + c15;
            float v = acc[ct][j] + b_ih[DD + c] + b_hh[DD + c];
            zg[ct * 4 + j] = 1.f / (1.f + __expf(-v));
        }
    __syncthreads();

    // ---- gate n (separate i/h accumulators) ----
    stageW(WA, Wih + 32768, tid);
    stageW(WB, Whh + 32768, tid);
    __syncthreads();
    f32x4 acch[8];
#pragma unroll
    for (int ct = 0; ct < 8; ++ct) {
        acc[ct] = (f32x4){0.f, 0.f, 0.f, 0.f};
        acch[ct] = (f32x4){0.f, 0.f, 0.f, 0.f};
    }
#pragma unroll 1
    for (int s = 0; s < 4; ++s) {
        bf16x8 ai = fragG(agg, arow, s * 32 + 8 * hi);
        bf16x8 ah = fragG(hbf, arow, s * 32 + 8 * hi);
#pragma unroll
        for (int ct = 0; ct < 8; ++ct) {
            acc[ct]  = MFMA16(ai, fragL(WA, lane, s, ct * 16 + c15), acc[ct]);
            acch[ct] = MFMA16(ah, fragL(WB, lane, s, ct * 16 + c15), acch[ct]);
        }
    }
    __syncthreads();   // done reading WA/WB

    // ---- GRU combine; h_new -> LDS (overlay WA); stage W_out -> WB ----
    unsigned short* Hu = reinterpret_cast<unsigned short*>(WA);
#pragma unroll
    for (int ct = 0; ct < 8; ++ct)
#pragma unroll
        for (int j = 0; j < 4; ++j) {
            int c = ct * 16 + c15;
            int rloc = w * 16 + 4 * hi + j;
            long r = base + rloc;
            long rr = (r < M) ? r : (M - 1);
            float inb = acc[ct][j] + b_ih[2 * DD + c];
            float hnb = acch[ct][j] + b_hh[2 * DD + c];
            float n = tanhf(inb + rg[ct * 4 + j] * hnb);
            float hv = bf2f(hbf[rr * DD + c]);
            float z = zg[ct * 4 + j];
            float hnew = (1.f - z) * n + z * hv;
            Hu[rloc * DD + ((c >> 3) ^ (rloc & 15)) * 8 + (c & 7)] = f2bf(hnew);
        }
    stageW(WB, Wo, tid);
    __syncthreads();

    // ---- out = h_new @ W_out^T + b_out ----
#pragma unroll
    for (int ct = 0; ct < 8; ++ct) acc[ct] = (f32x4){0.f, 0.f, 0.f, 0.f};
#pragma unroll 1
    for (int s = 0; s < 4; ++s) {
        bf16x8 a = fragL(WA, lane, s, w * 16 + c15);
#pragma unroll
        for (int ct = 0; ct < 8; ++ct)
            acc[ct] = MFMA16(a, fragL(WB, lane, s, ct * 16 + c15), acc[ct]);
    }
#pragma unroll
    for (int ct = 0; ct < 8; ++ct)
#pragma unroll
        for (int j = 0; j < 4; ++j) {
            long r = base + w * 16 + 4 * hi + j;
            if (r < M) out[r * DD + ct * 16 + c15] = acc[ct][j] + b_out[ct * 16 + c15];
        }
}

extern "C" void kernel_launch(void* const* d_in, const int* in_sizes, int n_in,
                              void* d_out, int out_size, void* d_ws, size_t ws_size,
                              hipStream_t stream) {
    const float* x     = (const float*)d_in[0];
    const int*   ei    = (const int*)d_in[1];
    const float* W_in  = (const float*)d_in[2];
    const float* b_in  = (const float*)d_in[3];
    const float* W_msg = (const float*)d_in[4];
    const float* W_ih  = (const float*)d_in[5];
    const float* b_ih  = (const float*)d_in[6];
    const float* W_hh  = (const float*)d_in[7];
    const float* b_hh  = (const float*)d_in[8];
    const float* W_out = (const float*)d_in[9];
    const float* b_out = (const float*)d_in[10];

    const int N = in_sizes[0] / DD;     // 100000
    const int E = in_sizes[1] / 2;      // 1600000
    float* out = (float*)d_out;

    // ws: [0, 512KB) weights bf16 | h_bf | m_bf | agg_bf  (each 25.6MB)
    const size_t slotE = (size_t)N * DD;
    unsigned short* wb     = (unsigned short*)d_ws;
    unsigned short* h_bf   = (unsigned short*)((char*)d_ws + (1 << 19));
    unsigned short* m_bf   = h_bf + slotE;
    unsigned short* agg_bf = m_bf + slotE;

    // CSR scratch in d_out (dead until gru8 writes out at the very end)
    const int NB = (N + 1023) / 1024;
    int* cnt    = (int*)d_out;
    int* off    = cnt + N;
    int* bucket = off + N + 1;
    int* bsum   = bucket + E;
    int* bbase  = bsum + NB;

    dim3 blk(256);
    const int gblocks = (N + 63) / 64;   // 1563

    wconv<<<(147456 + 255) / 256, blk, 0, stream>>>(W_in, W_msg, W_ih, W_hh, W_out, wb);
    zero_f4<<<128, blk, 0, stream>>>((float4*)cnt, (long)(N / 4));
    k12<<<gblocks, blk, 0, stream>>>(x, wb, wb + 16384, b_in, h_bf, m_bf, N);
    hist_dst<<<(E + 255) / 256, blk, 0, stream>>>(ei, cnt, E);
    scanA<<<NB, blk, 0, stream>>>(cnt, off, bsum, N);
    scanB<<<1, 128, 0, stream>>>(bsum, bbase, NB);
    scanC<<<NB, blk, 0, stream>>>(off, cnt, bbase, N, E);
    fill_bucket<<<(E + 255) / 256, blk, 0, stream>>>(ei, cnt, bucket, E);
    gather_sum_bf<<<(N + 3) / 4, blk, 0, stream>>>(m_bf, off, bucket, agg_bf, N);
    gru8<<<gblocks, blk, 0, stream>>>(agg_bf, h_bf, wb + 32768, wb + 81920, wb + 131072,
                                      b_ih, b_hh, b_out, out, N);
}

// Round 5
// 406.303 us; speedup vs baseline: 100.8615x; 1.0203x over previous
//
#include <hip/hip_runtime.h>
#include <math.h>

#define DD 128
#define RING 32
#define MAXB 400      // >= nbc = ceil(N/256)
#define CAPSH 13      // 8192 entries per coarse bin (avg 4092 for this dataset)

using bf16x8 = __attribute__((ext_vector_type(8))) short;
using f32x4  = __attribute__((ext_vector_type(4))) float;

__device__ inline unsigned short f2bf(float f) {
    unsigned int u = __float_as_uint(f);
    unsigned int r = (u + 0x7fffu + ((u >> 16) & 1u)) >> 16;   // RNE
    return (unsigned short)r;
}
__device__ inline float bf2f(unsigned short h) {
    return __uint_as_float(((unsigned int)h) << 16);
}

#define MFMA16(a, b, c) __builtin_amdgcn_mfma_f32_16x16x32_bf16((a), (b), (c), 0, 0, 0)

// Stage a 128x128 bf16 weight matrix (row-major [n][k]) into LDS, 16B chunks
// XOR-swizzled: chunk ch of row n lands at n*16 + (ch ^ (n&15)).
__device__ inline void stageW(float4* lds, const unsigned short* W, int tid) {
    const float4* src = reinterpret_cast<const float4*>(W);
#pragma unroll
    for (int it = 0; it < 8; ++it) {
        int i = tid + it * 256;
        int n = i >> 4, ch = i & 15;
        lds[n * 16 + (ch ^ (n & 15))] = src[i];
    }
}

__device__ inline bf16x8 fragL(const float4* lds, int lane, int s, int r) {
    float4 v = lds[r * 16 + (((s << 2) + (lane >> 4)) ^ (r & 15))];
    return __builtin_bit_cast(bf16x8, v);
}

__device__ inline bf16x8 fragG(const unsigned short* A, long row, int koff) {
    float4 v = *reinterpret_cast<const float4*>(A + row * DD + koff);
    return __builtin_bit_cast(bf16x8, v);
}

__device__ inline bf16x8 fragGF(const float* A, long row, int koff) {
    const float4* p = reinterpret_cast<const float4*>(A + row * DD + koff);
    float4 a = p[0], b = p[1];
    bf16x8 r;
    r[0] = f2bf(a.x); r[1] = f2bf(a.y); r[2] = f2bf(a.z); r[3] = f2bf(a.w);
    r[4] = f2bf(b.x); r[5] = f2bf(b.y); r[6] = f2bf(b.z); r[7] = f2bf(b.w);
    return r;
}

// ---------------- small zero ----------------
__global__ __launch_bounds__(256) void zero_ints(int* __restrict__ p, int n) {
    int i = blockIdx.x * 256 + threadIdx.x;
    if (i < n) p[i] = 0;
}

// ---------------- weight convert to bf16 (+ W_msg transpose) ----------------
__global__ __launch_bounds__(256) void wconv(
    const float* __restrict__ W_in, const float* __restrict__ W_msg,
    const float* __restrict__ W_ih, const float* __restrict__ W_hh,
    const float* __restrict__ W_out, unsigned short* __restrict__ wb)
{
    int i = blockIdx.x * 256 + threadIdx.x;
    if (i < 16384) wb[i] = f2bf(W_in[i]);
    else if (i < 32768) {
        int j = i - 16384; int n = j >> 7, k = j & 127;
        wb[i] = f2bf(W_msg[k * DD + n]);       // transpose
    }
    else if (i < 81920)  wb[i] = f2bf(W_ih[i - 32768]);
    else if (i < 131072) wb[i] = f2bf(W_hh[i - 81920]);
    else if (i < 147456) wb[i] = f2bf(W_out[i - 131072]);
}

// ============ Pass 1: bin edges by dst>>8 with LDS write-combining ============
// Entry = (src<<8) | (dst&255), 4B. Per-block ring of 32 per bin; flush aligned
// 16-entry (64B) groups written back-to-back by one thread -> each bucket line
// dirtied once (R4 fill_bucket: 4B random stores -> 106MB line flush traffic).
__global__ __launch_bounds__(256) void bin_edges(
    const int* __restrict__ ei, int E, int nbc,
    unsigned int* __restrict__ bucket, int* __restrict__ gcur,
    int* __restrict__ govf, unsigned long long* __restrict__ ovf)
{
    __shared__ unsigned int ring[MAXB][RING];
    __shared__ int lres[MAXB], lfl[MAXB];
    const int tid = threadIdx.x;
    for (int b = tid; b < MAXB; b += 256) { lres[b] = 0; lfl[b] = 0; }
    __syncthreads();

    const int nt = (E + 255) >> 8;
    for (int t = blockIdx.x; t < nt; t += gridDim.x) {
        const int e = (t << 8) + tid;
        if (e < E) {
            const int d = ei[E + e];
            const int s = ei[e];
            const int b = d >> 8;
            const unsigned int ent = ((unsigned int)s << 8) | (unsigned int)(d & 255);
            const int pos = atomicAdd(&lres[b], 1);
            if (pos - lfl[b] >= RING) {       // lfl stable during this phase
                const int op = atomicAdd(govf, 1);
                ovf[op] = ((unsigned long long)(unsigned int)s << 32) | (unsigned int)d;
            } else {
                ring[b][pos & (RING - 1)] = ent;
            }
        }
        __syncthreads();
        // flush phase: bin bb always handled by the same thread (tid == bb%256)
        for (int bb = tid; bb < nbc; bb += 256) {
            const int res = lres[bb];
            const int fl = lfl[bb];
            const int lim = fl + RING;
            const bool drain = res > lim;     // overflow happened: drain ring fully
            const int hi = drain ? lim : res;
            const int avail = hi - fl;
            const int nf = drain ? avail : (avail & ~15);
            if (nf > 0) {
                const int gp = atomicAdd(&gcur[bb], nf);
                unsigned int* dst = bucket + ((size_t)bb << CAPSH) + gp;
                for (int k = 0; k < nf; ++k) dst[k] = ring[bb][(fl + k) & (RING - 1)];
            }
            lfl[bb] = drain ? res : fl + nf;
        }
        __syncthreads();
    }
    // final drain (residual <= 31)
    for (int bb = tid; bb < nbc; bb += 256) {
        const int res = lres[bb];
        const int fl = lfl[bb];
        const int avail = res - fl;
        if (avail > 0) {
            const int gp = atomicAdd(&gcur[bb], avail);
            unsigned int* dst = bucket + ((size_t)bb << CAPSH) + gp;
            for (int k = 0; k < avail; ++k) dst[k] = ring[bb][(fl + k) & (RING - 1)];
        }
    }
}

// ============ Pass 2: per-128-dst-row block, LDS f32 accumulate ============
// Block = half of a coarse bin (128 rows), 64KB f32 acc -> 2 blocks/CU.
// Waves partition rows by (row&3)==wave; ballot+ctz extracts hits; 4-deep
// pipelined 256B m-row gathers (L3-resident).
__global__ __launch_bounds__(256) void bin_reduce(
    const unsigned short* __restrict__ m,
    const unsigned int* __restrict__ bucket, const int* __restrict__ gcur,
    const int* __restrict__ govf, const unsigned long long* __restrict__ ovf,
    unsigned short* __restrict__ agg, int N)
{
    __shared__ float acc[128 * DD];
    const int tid = threadIdx.x, lane = tid & 63, wv = tid >> 6;
    const int cb = blockIdx.x >> 1, hf = blockIdx.x & 1;
    {
        float4* a4 = (float4*)acc;
        const float4 z = {0.f, 0.f, 0.f, 0.f};
        for (int i = tid; i < 128 * DD / 4; i += 256) a4[i] = z;
    }
    __syncthreads();

    const int cnt = gcur[cb];
    const unsigned int* bb = bucket + ((size_t)cb << CAPSH);
    for (int c0 = 0; c0 < cnt; c0 += 64) {
        const int idx = c0 + lane;
        const unsigned int ent = (idx < cnt) ? bb[idx] : 0u;
        const int dl = ent & 255;
        const bool mine = (idx < cnt) && ((dl >> 7) == hf) && ((dl & 3) == wv);
        unsigned long long mask = __ballot(mine);
        while (__popcll(mask) >= 4) {
            int l0 = __builtin_ctzll(mask); mask &= mask - 1;
            int l1 = __builtin_ctzll(mask); mask &= mask - 1;
            int l2 = __builtin_ctzll(mask); mask &= mask - 1;
            int l3 = __builtin_ctzll(mask); mask &= mask - 1;
            const unsigned int e0 = __shfl(ent, l0);
            const unsigned int e1 = __shfl(ent, l1);
            const unsigned int e2 = __shfl(ent, l2);
            const unsigned int e3 = __shfl(ent, l3);
            const unsigned int mv0 = *(const unsigned int*)(m + ((size_t)(e0 >> 8)) * DD + lane * 2);
            const unsigned int mv1 = *(const unsigned int*)(m + ((size_t)(e1 >> 8)) * DD + lane * 2);
            const unsigned int mv2 = *(const unsigned int*)(m + ((size_t)(e2 >> 8)) * DD + lane * 2);
            const unsigned int mv3 = *(const unsigned int*)(m + ((size_t)(e3 >> 8)) * DD + lane * 2);
            float* p0 = &acc[(e0 & 127) * DD + lane * 2];
            p0[0] += bf2f((unsigned short)(mv0 & 0xffff)); p0[1] += bf2f((unsigned short)(mv0 >> 16));
            float* p1 = &acc[(e1 & 127) * DD + lane * 2];
            p1[0] += bf2f((unsigned short)(mv1 & 0xffff)); p1[1] += bf2f((unsigned short)(mv1 >> 16));
            float* p2 = &acc[(e2 & 127) * DD + lane * 2];
            p2[0] += bf2f((unsigned short)(mv2 & 0xffff)); p2[1] += bf2f((unsigned short)(mv2 >> 16));
            float* p3 = &acc[(e3 & 127) * DD + lane * 2];
            p3[0] += bf2f((unsigned short)(mv3 & 0xffff)); p3[1] += bf2f((unsigned short)(mv3 >> 16));
        }
        while (mask) {
            int l0 = __builtin_ctzll(mask); mask &= mask - 1;
            const unsigned int e0 = __shfl(ent, l0);
            const unsigned int mv0 = *(const unsigned int*)(m + ((size_t)(e0 >> 8)) * DD + lane * 2);
            float* p0 = &acc[(e0 & 127) * DD + lane * 2];
            p0[0] += bf2f((unsigned short)(mv0 & 0xffff)); p0[1] += bf2f((unsigned short)(mv0 >> 16));
        }
    }

    // overflow entries (normally zero)
    const int novf = *govf;
    for (int i = 0; i < novf; ++i) {
        const unsigned long long v = ovf[i];
        const int d = (int)(v & 0xffffffffu);
        if ((d >> 8) != cb) continue;
        const int dl = d & 255;
        if ((dl >> 7) != hf || (dl & 3) != wv) continue;
        const int src = (int)(v >> 32);
        const unsigned int mv = *(const unsigned int*)(m + (size_t)src * DD + lane * 2);
        float* p = &acc[(dl & 127) * DD + lane * 2];
        p[0] += bf2f((unsigned short)(mv & 0xffff)); p[1] += bf2f((unsigned short)(mv >> 16));
    }
    __syncthreads();

    const long rbase = (long)cb * 256 + (long)hf * 128;
    for (int r = wv; r < 128; r += 4) {
        const long rg = rbase + r;
        if (rg < N) {
            const float a0 = acc[r * DD + lane * 2];
            const float a1 = acc[r * DD + lane * 2 + 1];
            const unsigned int pk = ((unsigned int)f2bf(a1) << 16) | f2bf(a0);
            *(unsigned int*)(agg + rg * DD + lane * 2) = pk;
        }
    }
}

// ---------------- k12: h = x@W_in^T + b_in ; m = h@W_msg  (fused) ----------------
__global__ __launch_bounds__(256) void k12(
    const float* __restrict__ x, const unsigned short* __restrict__ Wi,
    const unsigned short* __restrict__ Wm, const float* __restrict__ b_in,
    unsigned short* __restrict__ h_bf, unsigned short* __restrict__ m_bf, int M)
{
    __shared__ float4 WA[2048];   // W_in, then h tile (overlay)
    __shared__ float4 WB[2048];   // W_msgT
    const int tid = threadIdx.x;
    const int lane = tid & 63;
    const int w = tid >> 6;
    const int c15 = lane & 15;
    const int hi = lane >> 4;
    const long base = (long)blockIdx.x * 64;
    long arow = base + w * 16 + c15;
    if (arow >= M) arow = M - 1;

    stageW(WA, Wi, tid);
    stageW(WB, Wm, tid);
    __syncthreads();

    f32x4 acc[8];
#pragma unroll
    for (int ct = 0; ct < 8; ++ct) acc[ct] = (f32x4){0.f, 0.f, 0.f, 0.f};
#pragma unroll 1
    for (int s = 0; s < 4; ++s) {
        bf16x8 a = fragGF(x, arow, s * 32 + 8 * hi);
#pragma unroll
        for (int ct = 0; ct < 8; ++ct)
            acc[ct] = MFMA16(a, fragL(WA, lane, s, ct * 16 + c15), acc[ct]);
    }
    __syncthreads();   // all waves done reading WA before overlay

    unsigned short* Hu = reinterpret_cast<unsigned short*>(WA);
#pragma unroll
    for (int ct = 0; ct < 8; ++ct)
#pragma unroll
        for (int j = 0; j < 4; ++j) {
            int rloc = w * 16 + 4 * hi + j;
            long r = base + rloc;
            int c = ct * 16 + c15;
            float v = acc[ct][j] + b_in[c];
            unsigned short hv = f2bf(v);
            Hu[rloc * DD + ((c >> 3) ^ (rloc & 15)) * 8 + (c & 7)] = hv;
            if (r < M) h_bf[r * DD + c] = hv;
        }
    __syncthreads();

    // phase 2: m = h @ W_msg
#pragma unroll
    for (int ct = 0; ct < 8; ++ct) acc[ct] = (f32x4){0.f, 0.f, 0.f, 0.f};
#pragma unroll 1
    for (int s = 0; s < 4; ++s) {
        bf16x8 a = fragL(WA, lane, s, w * 16 + c15);
#pragma unroll
        for (int ct = 0; ct < 8; ++ct)
            acc[ct] = MFMA16(a, fragL(WB, lane, s, ct * 16 + c15), acc[ct]);
    }
#pragma unroll
    for (int ct = 0; ct < 8; ++ct)
#pragma unroll
        for (int j = 0; j < 4; ++j) {
            long r = base + w * 16 + 4 * hi + j;
            if (r < M) m_bf[r * DD + ct * 16 + c15] = f2bf(acc[ct][j]);
        }
}

// ---------------- gru8: gates + GRU + out = h_new@W_out^T + b_out ----------------
__global__ __launch_bounds__(256) void gru8(
    const unsigned short* __restrict__ agg, const unsigned short* __restrict__ hbf,
    const unsigned short* __restrict__ Wih, const unsigned short* __restrict__ Whh,
    const unsigned short* __restrict__ Wo,
    const float* __restrict__ b_ih, const float* __restrict__ b_hh,
    const float* __restrict__ b_out, float* __restrict__ out, int M)
{
    __shared__ float4 WA[2048];
    __shared__ float4 WB[2048];
    const int tid = threadIdx.x;
    const int lane = tid & 63;
    const int w = tid >> 6;
    const int c15 = lane & 15;
    const int hi = lane >> 4;
    const long base = (long)blockIdx.x * 64;
    long arow = base + w * 16 + c15;
    if (arow >= M) arow = M - 1;

    f32x4 acc[8];
    float rg[32], zg[32];

    // ---- gate r ----
    stageW(WA, Wih, tid);
    stageW(WB, Whh, tid);
    __syncthreads();
#pragma unroll
    for (int ct = 0; ct < 8; ++ct) acc[ct] = (f32x4){0.f, 0.f, 0.f, 0.f};
#pragma unroll 1
    for (int s = 0; s < 4; ++s) {
        bf16x8 ai = fragG(agg, arow, s * 32 + 8 * hi);
        bf16x8 ah = fragG(hbf, arow, s * 32 + 8 * hi);
#pragma unroll
        for (int ct = 0; ct < 8; ++ct) {
            acc[ct] = MFMA16(ai, fragL(WA, lane, s, ct * 16 + c15), acc[ct]);
            acc[ct] = MFMA16(ah, fragL(WB, lane, s, ct * 16 + c15), acc[ct]);
        }
    }
#pragma unroll
    for (int ct = 0; ct < 8; ++ct)
#pragma unroll
        for (int j = 0; j < 4; ++j) {
            int c = ct * 16 + c15;
            float v = acc[ct][j] + b_ih[c] + b_hh[c];
            rg[ct * 4 + j] = 1.f / (1.f + __expf(-v));
        }
    __syncthreads();

    // ---- gate z ----
    stageW(WA, Wih + 16384, tid);
    stageW(WB, Whh + 16384, tid);
    __syncthreads();
#pragma unroll
    for (int ct = 0; ct < 8; ++ct) acc[ct] = (f32x4){0.f, 0.f, 0.f, 0.f};
#pragma unroll 1
    for (int s = 0; s < 4; ++s) {
        bf16x8 ai = fragG(agg, arow, s * 32 + 8 * hi);
        bf16x8 ah = fragG(hbf, arow, s * 32 + 8 * hi);
#pragma unroll
        for (int ct = 0; ct < 8; ++ct) {
            acc[ct] = MFMA16(ai, fragL(WA, lane, s, ct * 16 + c15), acc[ct]);
            acc[ct] = MFMA16(ah, fragL(WB, lane, s, ct * 16 + c15), acc[ct]);
        }
    }
#pragma unroll
    for (int ct = 0; ct < 8; ++ct)
#pragma unroll
        for (int j = 0; j < 4; ++j) {
            int c = ct * 16 + c15;
            float v = acc[ct][j] + b_ih[DD + c] + b_hh[DD + c];
            zg[ct * 4 + j] = 1.f / (1.f + __expf(-v));
        }
    __syncthreads();

    // ---- gate n ----
    stageW(WA, Wih + 32768, tid);
    stageW(WB, Whh + 32768, tid);
    __syncthreads();
    f32x4 acch[8];
#pragma unroll
    for (int ct = 0; ct < 8; ++ct) {
        acc[ct] = (f32x4){0.f, 0.f, 0.f, 0.f};
        acch[ct] = (f32x4){0.f, 0.f, 0.f, 0.f};
    }
#pragma unroll 1
    for (int s = 0; s < 4; ++s) {
        bf16x8 ai = fragG(agg, arow, s * 32 + 8 * hi);
        bf16x8 ah = fragG(hbf, arow, s * 32 + 8 * hi);
#pragma unroll
        for (int ct = 0; ct < 8; ++ct) {
            acc[ct]  = MFMA16(ai, fragL(WA, lane, s, ct * 16 + c15), acc[ct]);
            acch[ct] = MFMA16(ah, fragL(WB, lane, s, ct * 16 + c15), acch[ct]);
        }
    }
    __syncthreads();

    // ---- GRU combine; h_new -> LDS (overlay WA); stage W_out -> WB ----
    unsigned short* Hu = reinterpret_cast<unsigned short*>(WA);
#pragma unroll
    for (int ct = 0; ct < 8; ++ct)
#pragma unroll
        for (int j = 0; j < 4; ++j) {
            int c = ct * 16 + c15;
            int rloc = w * 16 + 4 * hi + j;
            long r = base + rloc;
            long rr = (r < M) ? r : (M - 1);
            float inb = acc[ct][j] + b_ih[2 * DD + c];
            float hnb = acch[ct][j] + b_hh[2 * DD + c];
            float n = tanhf(inb + rg[ct * 4 + j] * hnb);
            float hv = bf2f(hbf[rr * DD + c]);
            float z = zg[ct * 4 + j];
            float hnew = (1.f - z) * n + z * hv;
            Hu[rloc * DD + ((c >> 3) ^ (rloc & 15)) * 8 + (c & 7)] = f2bf(hnew);
        }
    stageW(WB, Wo, tid);
    __syncthreads();

    // ---- out = h_new @ W_out^T + b_out ----
#pragma unroll
    for (int ct = 0; ct < 8; ++ct) acc[ct] = (f32x4){0.f, 0.f, 0.f, 0.f};
#pragma unroll 1
    for (int s = 0; s < 4; ++s) {
        bf16x8 a = fragL(WA, lane, s, w * 16 + c15);
#pragma unroll
        for (int ct = 0; ct < 8; ++ct)
            acc[ct] = MFMA16(a, fragL(WB, lane, s, ct * 16 + c15), acc[ct]);
    }
#pragma unroll
    for (int ct = 0; ct < 8; ++ct)
#pragma unroll
        for (int j = 0; j < 4; ++j) {
            long r = base + w * 16 + 4 * hi + j;
            if (r < M) out[r * DD + ct * 16 + c15] = acc[ct][j] + b_out[ct * 16 + c15];
        }
}

extern "C" void kernel_launch(void* const* d_in, const int* in_sizes, int n_in,
                              void* d_out, int out_size, void* d_ws, size_t ws_size,
                              hipStream_t stream) {
    const float* x     = (const float*)d_in[0];
    const int*   ei    = (const int*)d_in[1];
    const float* W_in  = (const float*)d_in[2];
    const float* b_in  = (const float*)d_in[3];
    const float* W_msg = (const float*)d_in[4];
    const float* W_ih  = (const float*)d_in[5];
    const float* b_ih  = (const float*)d_in[6];
    const float* W_hh  = (const float*)d_in[7];
    const float* b_hh  = (const float*)d_in[8];
    const float* W_out = (const float*)d_in[9];
    const float* b_out = (const float*)d_in[10];

    const int N = in_sizes[0] / DD;     // 100000
    const int E = in_sizes[1] / 2;      // 1600000
    float* out = (float*)d_out;

    // ws: [0, 512KB) weights bf16 | h_bf | m_bf | agg_bf  (each 25.6MB)
    const size_t slotE = (size_t)N * DD;
    unsigned short* wb     = (unsigned short*)d_ws;
    unsigned short* h_bf   = (unsigned short*)((char*)d_ws + (1 << 19));
    unsigned short* m_bf   = h_bf + slotE;
    unsigned short* agg_bf = m_bf + slotE;

    // bin scratch in d_out (dead until gru8 writes out at the very end):
    // bucket [nbc<<13] u32 @ 0 (12.8MB) | gcur int[512] @ 16MB | govf | ovf u64[8192]
    const int nbc = (N + 255) >> 8;     // 391
    unsigned int* bucket = (unsigned int*)d_out;
    int* gcur = (int*)((char*)d_out + (16u << 20));
    int* govf = gcur + 512;
    unsigned long long* ovf = (unsigned long long*)(gcur + 1024);

    dim3 blk(256);
    const int gblocks = (N + 63) / 64;   // 1563

    wconv<<<(147456 + 255) / 256, blk, 0, stream>>>(W_in, W_msg, W_ih, W_hh, W_out, wb);
    zero_ints<<<4, blk, 0, stream>>>(gcur, 1024);
    bin_edges<<<256, blk, 0, stream>>>(ei, E, nbc, bucket, gcur, govf, ovf);
    k12<<<gblocks, blk, 0, stream>>>(x, wb, wb + 16384, b_in, h_bf, m_bf, N);
    bin_reduce<<<nbc * 2, blk, 0, stream>>>(m_bf, bucket, gcur, govf, ovf, agg_bf, N);
    gru8<<<gblocks, blk, 0, stream>>>(agg_bf, h_bf, wb + 32768, wb + 81920, wb + 131072,
                                      b_ih, b_hh, b_out, out, N);
}

// Round 6
// 307.734 us; speedup vs baseline: 133.1678x; 1.3203x over previous
//
#include <hip/hip_runtime.h>
#include <math.h>

#define DD 128
#define RING 32
#define MAXB 400      // >= nbc = ceil(N/256)
#define CAPSH 13      // 8192 entries per coarse bin (avg 4092 for this dataset)
#define WCAP 504      // per-wave compacted list capacity (expected ~256)

using bf16x8 = __attribute__((ext_vector_type(8))) short;
using f32x4  = __attribute__((ext_vector_type(4))) float;

__device__ inline unsigned short f2bf(float f) {
    unsigned int u = __float_as_uint(f);
    unsigned int r = (u + 0x7fffu + ((u >> 16) & 1u)) >> 16;   // RNE
    return (unsigned short)r;
}
__device__ inline float bf2f(unsigned short h) {
    return __uint_as_float(((unsigned int)h) << 16);
}

#define MFMA16(a, b, c) __builtin_amdgcn_mfma_f32_16x16x32_bf16((a), (b), (c), 0, 0, 0)

// Stage a 128x128 bf16 weight matrix (row-major [n][k]) into LDS, 16B chunks
// XOR-swizzled: chunk ch of row n lands at n*16 + (ch ^ (n&15)).
__device__ inline void stageW(float4* lds, const unsigned short* W, int tid) {
    const float4* src = reinterpret_cast<const float4*>(W);
#pragma unroll
    for (int it = 0; it < 8; ++it) {
        int i = tid + it * 256;
        int n = i >> 4, ch = i & 15;
        lds[n * 16 + (ch ^ (n & 15))] = src[i];
    }
}

__device__ inline bf16x8 fragL(const float4* lds, int lane, int s, int r) {
    float4 v = lds[r * 16 + (((s << 2) + (lane >> 4)) ^ (r & 15))];
    return __builtin_bit_cast(bf16x8, v);
}

__device__ inline bf16x8 fragG(const unsigned short* A, long row, int koff) {
    float4 v = *reinterpret_cast<const float4*>(A + row * DD + koff);
    return __builtin_bit_cast(bf16x8, v);
}

__device__ inline bf16x8 fragGF(const float* A, long row, int koff) {
    const float4* p = reinterpret_cast<const float4*>(A + row * DD + koff);
    float4 a = p[0], b = p[1];
    bf16x8 r;
    r[0] = f2bf(a.x); r[1] = f2bf(a.y); r[2] = f2bf(a.z); r[3] = f2bf(a.w);
    r[4] = f2bf(b.x); r[5] = f2bf(b.y); r[6] = f2bf(b.z); r[7] = f2bf(b.w);
    return r;
}

// ---------------- small zero ----------------
__global__ __launch_bounds__(256) void zero_ints(int* __restrict__ p, int n) {
    int i = blockIdx.x * 256 + threadIdx.x;
    if (i < n) p[i] = 0;
}

// ---------------- weight convert to bf16 (+ W_msg transpose) ----------------
__global__ __launch_bounds__(256) void wconv(
    const float* __restrict__ W_in, const float* __restrict__ W_msg,
    const float* __restrict__ W_ih, const float* __restrict__ W_hh,
    const float* __restrict__ W_out, unsigned short* __restrict__ wb)
{
    int i = blockIdx.x * 256 + threadIdx.x;
    if (i < 16384) wb[i] = f2bf(W_in[i]);
    else if (i < 32768) {
        int j = i - 16384; int n = j >> 7, k = j & 127;
        wb[i] = f2bf(W_msg[k * DD + n]);       // transpose
    }
    else if (i < 81920)  wb[i] = f2bf(W_ih[i - 32768]);
    else if (i < 131072) wb[i] = f2bf(W_hh[i - 81920]);
    else if (i < 147456) wb[i] = f2bf(W_out[i - 131072]);
}

// ============ Pass 1: bin edges by dst>>8 with LDS write-combining ============
__global__ __launch_bounds__(256) void bin_edges(
    const int* __restrict__ ei, int E, int nbc,
    unsigned int* __restrict__ bucket, int* __restrict__ gcur,
    int* __restrict__ govf, unsigned long long* __restrict__ ovf)
{
    __shared__ unsigned int ring[MAXB][RING];
    __shared__ int lres[MAXB], lfl[MAXB];
    const int tid = threadIdx.x;
    for (int b = tid; b < MAXB; b += 256) { lres[b] = 0; lfl[b] = 0; }
    __syncthreads();

    const int nt = (E + 255) >> 8;
    for (int t = blockIdx.x; t < nt; t += gridDim.x) {
        const int e = (t << 8) + tid;
        if (e < E) {
            const int d = ei[E + e];
            const int s = ei[e];
            const int b = d >> 8;
            const unsigned int ent = ((unsigned int)s << 8) | (unsigned int)(d & 255);
            const int pos = atomicAdd(&lres[b], 1);
            if (pos - lfl[b] >= RING) {
                const int op = atomicAdd(govf, 1);
                ovf[op] = ((unsigned long long)(unsigned int)s << 32) | (unsigned int)d;
            } else {
                ring[b][pos & (RING - 1)] = ent;
            }
        }
        __syncthreads();
        for (int bb = tid; bb < nbc; bb += 256) {
            const int res = lres[bb];
            const int fl = lfl[bb];
            const int lim = fl + RING;
            const bool drain = res > lim;
            const int hi = drain ? lim : res;
            const int avail = hi - fl;
            const int nf = drain ? avail : (avail & ~15);
            if (nf > 0) {
                const int gp = atomicAdd(&gcur[bb], nf);
                unsigned int* dst = bucket + ((size_t)bb << CAPSH) + gp;
                for (int k = 0; k < nf; ++k) dst[k] = ring[bb][(fl + k) & (RING - 1)];
            }
            lfl[bb] = drain ? res : fl + nf;
        }
        __syncthreads();
    }
    for (int bb = tid; bb < nbc; bb += 256) {
        const int res = lres[bb];
        const int fl = lfl[bb];
        const int avail = res - fl;
        if (avail > 0) {
            const int gp = atomicAdd(&gcur[bb], avail);
            unsigned int* dst = bucket + ((size_t)bb << CAPSH) + gp;
            for (int k = 0; k < avail; ++k) dst[k] = ring[bb][(fl + k) & (RING - 1)];
        }
    }
}

// ============ Pass 2: per-64-dst-row block, compacted-list gather ============
// R5 redesign: 32KB acc + 8KB per-wave lists -> ~40KB LDS -> 4 blocks/CU
// (16 waves, 2x occupancy). Wave owns rows (dl&3)==wv (no cross-wave acc race).
// Phase A: one coalesced scan compacts each wave's entries into its LDS list.
// Phase B: 8-deep pipelined independent row gathers (no ballot in hot loop).
__global__ __launch_bounds__(256) void bin_reduce(
    const unsigned short* __restrict__ m,
    const unsigned int* __restrict__ bucket, const int* __restrict__ gcur,
    const int* __restrict__ govf, const unsigned long long* __restrict__ ovf,
    unsigned short* __restrict__ agg, int N)
{
    __shared__ float acc[64 * DD];             // 32KB
    __shared__ unsigned int wlist[4][WCAP];    // ~8KB
    const int tid = threadIdx.x, lane = tid & 63, wv = tid >> 6;
    const int cb = blockIdx.x >> 2, q = blockIdx.x & 3;

    {
        float4* a4 = (float4*)acc;
        const float4 z = {0.f, 0.f, 0.f, 0.f};
        for (int i = tid; i < 64 * DD / 4; i += 256) a4[i] = z;
    }

    int cnt = gcur[cb];
    if (cnt > (1 << CAPSH)) cnt = 1 << CAPSH;
    const unsigned int* bb = bucket + ((size_t)cb << CAPSH);

    // ---- Phase A: compact this wave's entries (rows q*64.., dl&3==wv) ----
    int nw = 0;
    bool ovfw = false;
    for (int c0 = 0; c0 < cnt; c0 += 64) {
        const int idx = c0 + lane;
        const unsigned int ent = (idx < cnt) ? bb[idx] : 0u;
        const int dl = ent & 255;
        const bool mine = (idx < cnt) && ((dl >> 6) == q) && ((dl & 3) == wv);
        const unsigned long long mask = __ballot(mine);
        if (mine) {
            const int p = __popcll(mask & ((1ull << lane) - 1));
            const int pos = nw + p;
            if (pos < WCAP) wlist[wv][pos] = ent;
            else ovfw = true;
        }
        nw += __popcll(mask);
    }
    const int nmy = (nw < WCAP) ? nw : WCAP;
    __syncthreads();   // acc zero complete; own-wave list ready

    // ---- Phase B: 8-deep pipelined gather-accumulate ----
    int i = 0;
    for (; i + 8 <= nmy; i += 8) {
        unsigned int e[8], mv[8];
#pragma unroll
        for (int j = 0; j < 8; ++j) e[j] = wlist[wv][i + j];
#pragma unroll
        for (int j = 0; j < 8; ++j)
            mv[j] = *(const unsigned int*)(m + ((size_t)(e[j] >> 8)) * DD + lane * 2);
#pragma unroll
        for (int j = 0; j < 8; ++j) {
            float2* p = (float2*)&acc[(e[j] & 63) * DD + lane * 2];
            float2 v = *p;
            v.x += bf2f((unsigned short)(mv[j] & 0xffff));
            v.y += bf2f((unsigned short)(mv[j] >> 16));
            *p = v;
        }
    }
    for (; i < nmy; ++i) {
        const unsigned int e0 = wlist[wv][i];
        const unsigned int mv0 = *(const unsigned int*)(m + ((size_t)(e0 >> 8)) * DD + lane * 2);
        float2* p = (float2*)&acc[(e0 & 63) * DD + lane * 2];
        float2 v = *p;
        v.x += bf2f((unsigned short)(mv0 & 0xffff));
        v.y += bf2f((unsigned short)(mv0 >> 16));
        *p = v;
    }

    // ---- rare: list overflow fallback (ordinals >= WCAP), ballot-extract ----
    if (__ballot(ovfw)) {
        if (ovfw) {
            int cum = 0;
            for (int c0 = 0; c0 < cnt; c0 += 64) {
                const int idx = c0 + lane;
                const unsigned int ent = (idx < cnt) ? bb[idx] : 0u;
                const int dl = ent & 255;
                const bool mine = (idx < cnt) && ((dl >> 6) == q) && ((dl & 3) == wv);
                unsigned long long mask = __ballot(mine);
                unsigned long long mm = mask;
                int k = 0;
                while (mm) {
                    const int l = __builtin_ctzll(mm); mm &= mm - 1;
                    if (cum + k >= WCAP) {
                        const unsigned int ee = __shfl(ent, l);
                        const unsigned int mvv = *(const unsigned int*)(m + ((size_t)(ee >> 8)) * DD + lane * 2);
                        float2* p = (float2*)&acc[(ee & 63) * DD + lane * 2];
                        float2 v = *p;
                        v.x += bf2f((unsigned short)(mvv & 0xffff));
                        v.y += bf2f((unsigned short)(mvv >> 16));
                        *p = v;
                    }
                    ++k;
                }
                cum += __popcll(mask);
            }
        }
    }

    // ---- rare: ring-overflow entries from bin_edges ----
    const int novf = *govf;
    for (int i2 = 0; i2 < novf; ++i2) {
        const unsigned long long v = ovf[i2];
        const int d = (int)(v & 0xffffffffu);
        if ((d >> 8) != cb) continue;
        const int dl = d & 255;
        if ((dl >> 6) != q || (dl & 3) != wv) continue;
        const int src = (int)(v >> 32);
        const unsigned int mv = *(const unsigned int*)(m + (size_t)src * DD + lane * 2);
        float2* p = (float2*)&acc[(dl & 63) * DD + lane * 2];
        float2 vv = *p;
        vv.x += bf2f((unsigned short)(mv & 0xffff));
        vv.y += bf2f((unsigned short)(mv >> 16));
        *p = vv;
    }
    __syncthreads();

    const long rbase = (long)cb * 256 + (long)q * 64;
    for (int r = wv; r < 64; r += 4) {
        const long rg = rbase + r;
        if (rg < N) {
            const float a0 = acc[r * DD + lane * 2];
            const float a1 = acc[r * DD + lane * 2 + 1];
            const unsigned int pk = ((unsigned int)f2bf(a1) << 16) | f2bf(a0);
            *(unsigned int*)(agg + rg * DD + lane * 2) = pk;
        }
    }
}

// ---------------- k12: h = x@W_in^T + b_in ; m = h@W_msg  (fused) ----------------
__global__ __launch_bounds__(256) void k12(
    const float* __restrict__ x, const unsigned short* __restrict__ Wi,
    const unsigned short* __restrict__ Wm, const float* __restrict__ b_in,
    unsigned short* __restrict__ h_bf, unsigned short* __restrict__ m_bf, int M)
{
    __shared__ float4 WA[2048];   // W_in, then h tile (overlay)
    __shared__ float4 WB[2048];   // W_msgT
    const int tid = threadIdx.x;
    const int lane = tid & 63;
    const int w = tid >> 6;
    const int c15 = lane & 15;
    const int hi = lane >> 4;
    const long base = (long)blockIdx.x * 64;
    long arow = base + w * 16 + c15;
    if (arow >= M) arow = M - 1;

    stageW(WA, Wi, tid);
    stageW(WB, Wm, tid);
    __syncthreads();

    f32x4 acc[8];
#pragma unroll
    for (int ct = 0; ct < 8; ++ct) acc[ct] = (f32x4){0.f, 0.f, 0.f, 0.f};
#pragma unroll 1
    for (int s = 0; s < 4; ++s) {
        bf16x8 a = fragGF(x, arow, s * 32 + 8 * hi);
#pragma unroll
        for (int ct = 0; ct < 8; ++ct)
            acc[ct] = MFMA16(a, fragL(WA, lane, s, ct * 16 + c15), acc[ct]);
    }
    __syncthreads();

    unsigned short* Hu = reinterpret_cast<unsigned short*>(WA);
#pragma unroll
    for (int ct = 0; ct < 8; ++ct)
#pragma unroll
        for (int j = 0; j < 4; ++j) {
            int rloc = w * 16 + 4 * hi + j;
            long r = base + rloc;
            int c = ct * 16 + c15;
            float v = acc[ct][j] + b_in[c];
            unsigned short hv = f2bf(v);
            Hu[rloc * DD + ((c >> 3) ^ (rloc & 15)) * 8 + (c & 7)] = hv;
            if (r < M) h_bf[r * DD + c] = hv;
        }
    __syncthreads();

    // phase 2: m = h @ W_msg
#pragma unroll
    for (int ct = 0; ct < 8; ++ct) acc[ct] = (f32x4){0.f, 0.f, 0.f, 0.f};
#pragma unroll 1
    for (int s = 0; s < 4; ++s) {
        bf16x8 a = fragL(WA, lane, s, w * 16 + c15);
#pragma unroll
        for (int ct = 0; ct < 8; ++ct)
            acc[ct] = MFMA16(a, fragL(WB, lane, s, ct * 16 + c15), acc[ct]);
    }
#pragma unroll
    for (int ct = 0; ct < 8; ++ct)
#pragma unroll
        for (int j = 0; j < 4; ++j) {
            long r = base + w * 16 + 4 * hi + j;
            if (r < M) m_bf[r * DD + ct * 16 + c15] = f2bf(acc[ct][j]);
        }
}

// ---------------- gru8: gates + GRU + out = h_new@W_out^T + b_out ----------------
__global__ __launch_bounds__(256) void gru8(
    const unsigned short* __restrict__ agg, const unsigned short* __restrict__ hbf,
    const unsigned short* __restrict__ Wih, const unsigned short* __restrict__ Whh,
    const unsigned short* __restrict__ Wo,
    const float* __restrict__ b_ih, const float* __restrict__ b_hh,
    const float* __restrict__ b_out, float* __restrict__ out, int M)
{
    __shared__ float4 WA[2048];
    __shared__ float4 WB[2048];
    const int tid = threadIdx.x;
    const int lane = tid & 63;
    const int w = tid >> 6;
    const int c15 = lane & 15;
    const int hi = lane >> 4;
    const long base = (long)blockIdx.x * 64;
    long arow = base + w * 16 + c15;
    if (arow >= M) arow = M - 1;

    f32x4 acc[8];
    float rg[32], zg[32];

    // ---- gate r ----
    stageW(WA, Wih, tid);
    stageW(WB, Whh, tid);
    __syncthreads();
#pragma unroll
    for (int ct = 0; ct < 8; ++ct) acc[ct] = (f32x4){0.f, 0.f, 0.f, 0.f};
#pragma unroll 1
    for (int s = 0; s < 4; ++s) {
        bf16x8 ai = fragG(agg, arow, s * 32 + 8 * hi);
        bf16x8 ah = fragG(hbf, arow, s * 32 + 8 * hi);
#pragma unroll
        for (int ct = 0; ct < 8; ++ct) {
            acc[ct] = MFMA16(ai, fragL(WA, lane, s, ct * 16 + c15), acc[ct]);
            acc[ct] = MFMA16(ah, fragL(WB, lane, s, ct * 16 + c15), acc[ct]);
        }
    }
#pragma unroll
    for (int ct = 0; ct < 8; ++ct)
#pragma unroll
        for (int j = 0; j < 4; ++j) {
            int c = ct * 16 + c15;
            float v = acc[ct][j] + b_ih[c] + b_hh[c];
            rg[ct * 4 + j] = 1.f / (1.f + __expf(-v));
        }
    __syncthreads();

    // ---- gate z ----
    stageW(WA, Wih + 16384, tid);
    stageW(WB, Whh + 16384, tid);
    __syncthreads();
#pragma unroll
    for (int ct = 0; ct < 8; ++ct) acc[ct] = (f32x4){0.f, 0.f, 0.f, 0.f};
#pragma unroll 1
    for (int s = 0; s < 4; ++s) {
        bf16x8 ai = fragG(agg, arow, s * 32 + 8 * hi);
        bf16x8 ah = fragG(hbf, arow, s * 32 + 8 * hi);
#pragma unroll
        for (int ct = 0; ct < 8; ++ct) {
            acc[ct] = MFMA16(ai, fragL(WA, lane, s, ct * 16 + c15), acc[ct]);
            acc[ct] = MFMA16(ah, fragL(WB, lane, s, ct * 16 + c15), acc[ct]);
        }
    }
#pragma unroll
    for (int ct = 0; ct < 8; ++ct)
#pragma unroll
        for (int j = 0; j < 4; ++j) {
            int c = ct * 16 + c15;
            float v = acc[ct][j] + b_ih[DD + c] + b_hh[DD + c];
            zg[ct * 4 + j] = 1.f / (1.f + __expf(-v));
        }
    __syncthreads();

    // ---- gate n ----
    stageW(WA, Wih + 32768, tid);
    stageW(WB, Whh + 32768, tid);
    __syncthreads();
    f32x4 acch[8];
#pragma unroll
    for (int ct = 0; ct < 8; ++ct) {
        acc[ct] = (f32x4){0.f, 0.f, 0.f, 0.f};
        acch[ct] = (f32x4){0.f, 0.f, 0.f, 0.f};
    }
#pragma unroll 1
    for (int s = 0; s < 4; ++s) {
        bf16x8 ai = fragG(agg, arow, s * 32 + 8 * hi);
        bf16x8 ah = fragG(hbf, arow, s * 32 + 8 * hi);
#pragma unroll
        for (int ct = 0; ct < 8; ++ct) {
            acc[ct]  = MFMA16(ai, fragL(WA, lane, s, ct * 16 + c15), acc[ct]);
            acch[ct] = MFMA16(ah, fragL(WB, lane, s, ct * 16 + c15), acch[ct]);
        }
    }
    __syncthreads();

    // ---- GRU combine; h_new -> LDS (overlay WA); stage W_out -> WB ----
    unsigned short* Hu = reinterpret_cast<unsigned short*>(WA);
#pragma unroll
    for (int ct = 0; ct < 8; ++ct)
#pragma unroll
        for (int j = 0; j < 4; ++j) {
            int c = ct * 16 + c15;
            int rloc = w * 16 + 4 * hi + j;
            long r = base + rloc;
            long rr = (r < M) ? r : (M - 1);
            float inb = acc[ct][j] + b_ih[2 * DD + c];
            float hnb = acch[ct][j] + b_hh[2 * DD + c];
            float n = tanhf(inb + rg[ct * 4 + j] * hnb);
            float hv = bf2f(hbf[rr * DD + c]);
            float z = zg[ct * 4 + j];
            float hnew = (1.f - z) * n + z * hv;
            Hu[rloc * DD + ((c >> 3) ^ (rloc & 15)) * 8 + (c & 7)] = f2bf(hnew);
        }
    stageW(WB, Wo, tid);
    __syncthreads();

    // ---- out = h_new @ W_out^T + b_out ----
#pragma unroll
    for (int ct = 0; ct < 8; ++ct) acc[ct] = (f32x4){0.f, 0.f, 0.f, 0.f};
#pragma unroll 1
    for (int s = 0; s < 4; ++s) {
        bf16x8 a = fragL(WA, lane, s, w * 16 + c15);
#pragma unroll
        for (int ct = 0; ct < 8; ++ct)
            acc[ct] = MFMA16(a, fragL(WB, lane, s, ct * 16 + c15), acc[ct]);
    }
#pragma unroll
    for (int ct = 0; ct < 8; ++ct)
#pragma unroll
        for (int j = 0; j < 4; ++j) {
            long r = base + w * 16 + 4 * hi + j;
            if (r < M) out[r * DD + ct * 16 + c15] = acc[ct][j] + b_out[ct * 16 + c15];
        }
}

extern "C" void kernel_launch(void* const* d_in, const int* in_sizes, int n_in,
                              void* d_out, int out_size, void* d_ws, size_t ws_size,
                              hipStream_t stream) {
    const float* x     = (const float*)d_in[0];
    const int*   ei    = (const int*)d_in[1];
    const float* W_in  = (const float*)d_in[2];
    const float* b_in  = (const float*)d_in[3];
    const float* W_msg = (const float*)d_in[4];
    const float* W_ih  = (const float*)d_in[5];
    const float* b_ih  = (const float*)d_in[6];
    const float* W_hh  = (const float*)d_in[7];
    const float* b_hh  = (const float*)d_in[8];
    const float* W_out = (const float*)d_in[9];
    const float* b_out = (const float*)d_in[10];

    const int N = in_sizes[0] / DD;     // 100000
    const int E = in_sizes[1] / 2;      // 1600000
    float* out = (float*)d_out;

    // ws: [0, 512KB) weights bf16 | h_bf | m_bf | agg_bf  (each 25.6MB)
    const size_t slotE = (size_t)N * DD;
    unsigned short* wb     = (unsigned short*)d_ws;
    unsigned short* h_bf   = (unsigned short*)((char*)d_ws + (1 << 19));
    unsigned short* m_bf   = h_bf + slotE;
    unsigned short* agg_bf = m_bf + slotE;

    // bin scratch in d_out (dead until gru8 writes out at the very end)
    const int nbc = (N + 255) >> 8;     // 391
    unsigned int* bucket = (unsigned int*)d_out;
    int* gcur = (int*)((char*)d_out + (16u << 20));
    int* govf = gcur + 512;
    unsigned long long* ovf = (unsigned long long*)(gcur + 1024);

    dim3 blk(256);
    const int gblocks = (N + 63) / 64;   // 1563

    wconv<<<(147456 + 255) / 256, blk, 0, stream>>>(W_in, W_msg, W_ih, W_hh, W_out, wb);
    zero_ints<<<4, blk, 0, stream>>>(gcur, 1024);
    bin_edges<<<256, blk, 0, stream>>>(ei, E, nbc, bucket, gcur, govf, ovf);
    k12<<<gblocks, blk, 0, stream>>>(x, wb, wb + 16384, b_in, h_bf, m_bf, N);
    bin_reduce<<<nbc * 4, blk, 0, stream>>>(m_bf, bucket, gcur, govf, ovf, agg_bf, N);
    gru8<<<gblocks, blk, 0, stream>>>(agg_bf, h_bf, wb + 32768, wb + 81920, wb + 131072,
                                      b_ih, b_hh, b_out, out, N);
}

// Round 7
// 262.829 us; speedup vs baseline: 155.9203x; 1.1709x over previous
//
#include <hip/hip_runtime.h>
#include <math.h>

#define DD 128
#define RING 32
#define MAXB 400      // >= nbc = ceil(N/256)
#define CAPSH 13      // 8192 entries per coarse bin (avg 4092 for this dataset)
#define WCAP 248      // per-wave compacted list capacity (expected ~128, sigma ~11)
#define NBIN_BLOCKS 256

using bf16x8 = __attribute__((ext_vector_type(8))) short;
using f32x4  = __attribute__((ext_vector_type(4))) float;

__device__ inline unsigned short f2bf(float f) {
    unsigned int u = __float_as_uint(f);
    unsigned int r = (u + 0x7fffu + ((u >> 16) & 1u)) >> 16;   // RNE
    return (unsigned short)r;
}
__device__ inline float bf2f(unsigned short h) {
    return __uint_as_float(((unsigned int)h) << 16);
}

#define MFMA16(a, b, c) __builtin_amdgcn_mfma_f32_16x16x32_bf16((a), (b), (c), 0, 0, 0)

__device__ inline void stageW(float4* lds, const unsigned short* W, int tid) {
    const float4* src = reinterpret_cast<const float4*>(W);
#pragma unroll
    for (int it = 0; it < 8; ++it) {
        int i = tid + it * 256;
        int n = i >> 4, ch = i & 15;
        lds[n * 16 + (ch ^ (n & 15))] = src[i];
    }
}

__device__ inline bf16x8 fragL(const float4* lds, int lane, int s, int r) {
    float4 v = lds[r * 16 + (((s << 2) + (lane >> 4)) ^ (r & 15))];
    return __builtin_bit_cast(bf16x8, v);
}

__device__ inline bf16x8 fragG(const unsigned short* A, long row, int koff) {
    float4 v = *reinterpret_cast<const float4*>(A + row * DD + koff);
    return __builtin_bit_cast(bf16x8, v);
}

__device__ inline bf16x8 fragGF(const float* A, long row, int koff) {
    const float4* p = reinterpret_cast<const float4*>(A + row * DD + koff);
    float4 a = p[0], b = p[1];
    bf16x8 r;
    r[0] = f2bf(a.x); r[1] = f2bf(a.y); r[2] = f2bf(a.z); r[3] = f2bf(a.w);
    r[4] = f2bf(b.x); r[5] = f2bf(b.y); r[6] = f2bf(b.z); r[7] = f2bf(b.w);
    return r;
}

// ---------------- weight convert to bf16 (+ W_msg transpose) + gcur zero ----------------
__global__ __launch_bounds__(256) void wconv(
    const float* __restrict__ W_in, const float* __restrict__ W_msg,
    const float* __restrict__ W_ih, const float* __restrict__ W_hh,
    const float* __restrict__ W_out, unsigned short* __restrict__ wb,
    int* __restrict__ gcur)
{
    int i = blockIdx.x * 256 + threadIdx.x;
    if (i < 16384) wb[i] = f2bf(W_in[i]);
    else if (i < 32768) {
        int j = i - 16384; int n = j >> 7, k = j & 127;
        wb[i] = f2bf(W_msg[k * DD + n]);       // transpose
    }
    else if (i < 81920)  wb[i] = f2bf(W_ih[i - 32768]);
    else if (i < 131072) wb[i] = f2bf(W_hh[i - 81920]);
    else if (i < 147456) wb[i] = f2bf(W_out[i - 131072]);
    else if (i < 148480) gcur[i - 147456] = 0;
}

// ============ bin_edges body: bin edges by dst>>8, LDS write-combined ============
__device__ void bin_edges_body(char* smem, int bid,
    const int* __restrict__ ei, int E, int nbc,
    unsigned int* __restrict__ bucket, int* __restrict__ gcur,
    int* __restrict__ govf, unsigned long long* __restrict__ ovf)
{
    unsigned int (*ring)[RING] = (unsigned int (*)[RING])smem;            // 51200B
    int* lres = (int*)(smem + MAXB * RING * 4);                           // 1600B
    int* lfl  = lres + MAXB;                                              // 1600B
    const int tid = threadIdx.x;
    for (int b = tid; b < MAXB; b += 256) { lres[b] = 0; lfl[b] = 0; }
    __syncthreads();

    const int nt = (E + 255) >> 8;
    for (int t = bid; t < nt; t += NBIN_BLOCKS) {
        const int e = (t << 8) + tid;
        if (e < E) {
            const int d = ei[E + e];
            const int s = ei[e];
            const int b = d >> 8;
            const unsigned int ent = ((unsigned int)s << 8) | (unsigned int)(d & 255);
            const int pos = atomicAdd(&lres[b], 1);
            if (pos - lfl[b] >= RING) {
                const int op = atomicAdd(govf, 1);
                ovf[op] = ((unsigned long long)(unsigned int)s << 32) | (unsigned int)d;
            } else {
                ring[b][pos & (RING - 1)] = ent;
            }
        }
        __syncthreads();
        for (int bb = tid; bb < nbc; bb += 256) {
            const int res = lres[bb];
            const int fl = lfl[bb];
            const int lim = fl + RING;
            const bool drain = res > lim;
            const int hi = drain ? lim : res;
            const int avail = hi - fl;
            const int nf = drain ? avail : (avail & ~15);
            if (nf > 0) {
                const int gp = atomicAdd(&gcur[bb], nf);
                unsigned int* dst = bucket + ((size_t)bb << CAPSH) + gp;
                for (int k = 0; k < nf; ++k) dst[k] = ring[bb][(fl + k) & (RING - 1)];
            }
            lfl[bb] = drain ? res : fl + nf;
        }
        __syncthreads();
    }
    for (int bb = tid; bb < nbc; bb += 256) {
        const int res = lres[bb];
        const int fl = lfl[bb];
        const int avail = res - fl;
        if (avail > 0) {
            const int gp = atomicAdd(&gcur[bb], avail);
            unsigned int* dst = bucket + ((size_t)bb << CAPSH) + gp;
            for (int k = 0; k < avail; ++k) dst[k] = ring[bb][(fl + k) & (RING - 1)];
        }
    }
}

// ============ k12 body: h = x@W_in^T + b_in ; m = h@W_msg (fused) ============
__device__ void k12_body(char* smem, int bid,
    const float* __restrict__ x, const unsigned short* __restrict__ Wi,
    const unsigned short* __restrict__ Wm, const float* __restrict__ b_in,
    unsigned short* __restrict__ h_bf, unsigned short* __restrict__ m_bf, int M)
{
    float4* WA = (float4*)smem;             // 32KB: W_in, then h tile (overlay)
    float4* WB = (float4*)(smem + 32768);   // 32KB: W_msgT
    const int tid = threadIdx.x;
    const int lane = tid & 63;
    const int w = tid >> 6;
    const int c15 = lane & 15;
    const int hi = lane >> 4;
    const long base = (long)bid * 64;
    long arow = base + w * 16 + c15;
    if (arow >= M) arow = M - 1;

    stageW(WA, Wi, tid);
    stageW(WB, Wm, tid);
    __syncthreads();

    f32x4 acc[8];
#pragma unroll
    for (int ct = 0; ct < 8; ++ct) acc[ct] = (f32x4){0.f, 0.f, 0.f, 0.f};
#pragma unroll 1
    for (int s = 0; s < 4; ++s) {
        bf16x8 a = fragGF(x, arow, s * 32 + 8 * hi);
#pragma unroll
        for (int ct = 0; ct < 8; ++ct)
            acc[ct] = MFMA16(a, fragL(WA, lane, s, ct * 16 + c15), acc[ct]);
    }
    __syncthreads();

    unsigned short* Hu = reinterpret_cast<unsigned short*>(WA);
#pragma unroll
    for (int ct = 0; ct < 8; ++ct)
#pragma unroll
        for (int j = 0; j < 4; ++j) {
            int rloc = w * 16 + 4 * hi + j;
            long r = base + rloc;
            int c = ct * 16 + c15;
            float v = acc[ct][j] + b_in[c];
            unsigned short hv = f2bf(v);
            Hu[rloc * DD + ((c >> 3) ^ (rloc & 15)) * 8 + (c & 7)] = hv;
            if (r < M) h_bf[r * DD + c] = hv;
        }
    __syncthreads();

#pragma unroll
    for (int ct = 0; ct < 8; ++ct) acc[ct] = (f32x4){0.f, 0.f, 0.f, 0.f};
#pragma unroll 1
    for (int s = 0; s < 4; ++s) {
        bf16x8 a = fragL(WA, lane, s, w * 16 + c15);
#pragma unroll
        for (int ct = 0; ct < 8; ++ct)
            acc[ct] = MFMA16(a, fragL(WB, lane, s, ct * 16 + c15), acc[ct]);
    }
#pragma unroll
    for (int ct = 0; ct < 8; ++ct)
#pragma unroll
        for (int j = 0; j < 4; ++j) {
            long r = base + w * 16 + 4 * hi + j;
            if (r < M) m_bf[r * DD + ct * 16 + c15] = f2bf(acc[ct][j]);
        }
}

// ============ front: blockIdx-dispatched {bin_edges || k12} ============
__global__ __launch_bounds__(256) void front(
    const int* __restrict__ ei, int E, int nbc,
    unsigned int* __restrict__ bucket, int* __restrict__ gcur,
    int* __restrict__ govf, unsigned long long* __restrict__ ovf,
    const float* __restrict__ x, const unsigned short* __restrict__ Wi,
    const unsigned short* __restrict__ Wm, const float* __restrict__ b_in,
    unsigned short* __restrict__ h_bf, unsigned short* __restrict__ m_bf, int M)
{
    __shared__ char smem[65536];
    if (blockIdx.x < NBIN_BLOCKS)
        bin_edges_body(smem, blockIdx.x, ei, E, nbc, bucket, gcur, govf, ovf);
    else
        k12_body(smem, blockIdx.x - NBIN_BLOCKS, x, Wi, Wm, b_in, h_bf, m_bf, M);
}

// ============ bin_reduce: per-32-dst-row block, compacted-list gather ============
// R6: 16KB acc + 4KB lists -> 20KB LDS -> 8 blocks/CU (32 waves, 2x R5).
// Wave owns rows (dl&3)==wv within sub-block q=(dl>>5); 8-deep pipelined gathers.
__global__ __launch_bounds__(256, 8) void bin_reduce(
    const unsigned short* __restrict__ m,
    const unsigned int* __restrict__ bucket, const int* __restrict__ gcur,
    const int* __restrict__ govf, const unsigned long long* __restrict__ ovf,
    unsigned short* __restrict__ agg, int N)
{
    __shared__ float acc[32 * DD];             // 16KB
    __shared__ unsigned int wlist[4][WCAP];    // 3968B
    const int tid = threadIdx.x, lane = tid & 63, wv = tid >> 6;
    const int cb = blockIdx.x >> 3, q = blockIdx.x & 7;

    {
        float4* a4 = (float4*)acc;
        const float4 z = {0.f, 0.f, 0.f, 0.f};
        for (int i = tid; i < 32 * DD / 4; i += 256) a4[i] = z;
    }

    int cnt = gcur[cb];
    if (cnt > (1 << CAPSH)) cnt = 1 << CAPSH;
    const unsigned int* bb = bucket + ((size_t)cb << CAPSH);

    // ---- Phase A: compact this wave's entries (dl>>5==q, dl&3==wv) ----
    int nw = 0;
    bool ovfw = false;
    for (int c0 = 0; c0 < cnt; c0 += 64) {
        const int idx = c0 + lane;
        const unsigned int ent = (idx < cnt) ? bb[idx] : 0u;
        const int dl = ent & 255;
        const bool mine = (idx < cnt) && ((dl >> 5) == q) && ((dl & 3) == wv);
        const unsigned long long mask = __ballot(mine);
        if (mine) {
            const int p = __popcll(mask & ((1ull << lane) - 1));
            const int pos = nw + p;
            if (pos < WCAP) wlist[wv][pos] = ent;
            else ovfw = true;
        }
        nw += __popcll(mask);
    }
    const int nmy = (nw < WCAP) ? nw : WCAP;
    __syncthreads();

    // ---- Phase B: 8-deep pipelined gather-accumulate ----
    int i = 0;
    for (; i + 8 <= nmy; i += 8) {
        unsigned int e[8], mv[8];
#pragma unroll
        for (int j = 0; j < 8; ++j) e[j] = wlist[wv][i + j];
#pragma unroll
        for (int j = 0; j < 8; ++j)
            mv[j] = *(const unsigned int*)(m + ((size_t)(e[j] >> 8)) * DD + lane * 2);
#pragma unroll
        for (int j = 0; j < 8; ++j) {
            float2* p = (float2*)&acc[(e[j] & 31) * DD + lane * 2];
            float2 v = *p;
            v.x += bf2f((unsigned short)(mv[j] & 0xffff));
            v.y += bf2f((unsigned short)(mv[j] >> 16));
            *p = v;
        }
    }
    for (; i < nmy; ++i) {
        const unsigned int e0 = wlist[wv][i];
        const unsigned int mv0 = *(const unsigned int*)(m + ((size_t)(e0 >> 8)) * DD + lane * 2);
        float2* p = (float2*)&acc[(e0 & 31) * DD + lane * 2];
        float2 v = *p;
        v.x += bf2f((unsigned short)(mv0 & 0xffff));
        v.y += bf2f((unsigned short)(mv0 >> 16));
        *p = v;
    }

    // ---- rare: list overflow fallback (ordinals >= WCAP) ----
    if (__ballot(ovfw)) {
        if (ovfw) {
            int cum = 0;
            for (int c0 = 0; c0 < cnt; c0 += 64) {
                const int idx = c0 + lane;
                const unsigned int ent = (idx < cnt) ? bb[idx] : 0u;
                const int dl = ent & 255;
                const bool mine = (idx < cnt) && ((dl >> 5) == q) && ((dl & 3) == wv);
                unsigned long long mask = __ballot(mine);
                unsigned long long mm = mask;
                int k = 0;
                while (mm) {
                    const int l = __builtin_ctzll(mm); mm &= mm - 1;
                    if (cum + k >= WCAP) {
                        const unsigned int ee = __shfl(ent, l);
                        const unsigned int mvv = *(const unsigned int*)(m + ((size_t)(ee >> 8)) * DD + lane * 2);
                        float2* p = (float2*)&acc[(ee & 31) * DD + lane * 2];
                        float2 v = *p;
                        v.x += bf2f((unsigned short)(mvv & 0xffff));
                        v.y += bf2f((unsigned short)(mvv >> 16));
                        *p = v;
                    }
                    ++k;
                }
                cum += __popcll(mask);
            }
        }
    }

    // ---- rare: ring-overflow entries from bin_edges ----
    const int novf = *govf;
    for (int i2 = 0; i2 < novf; ++i2) {
        const unsigned long long v = ovf[i2];
        const int d = (int)(v & 0xffffffffu);
        if ((d >> 8) != cb) continue;
        const int dl = d & 255;
        if ((dl >> 5) != q || (dl & 3) != wv) continue;
        const int src = (int)(v >> 32);
        const unsigned int mv = *(const unsigned int*)(m + (size_t)src * DD + lane * 2);
        float2* p = (float2*)&acc[(dl & 31) * DD + lane * 2];
        float2 vv = *p;
        vv.x += bf2f((unsigned short)(mv & 0xffff));
        vv.y += bf2f((unsigned short)(mv >> 16));
        *p = vv;
    }
    __syncthreads();

    const long rbase = (long)cb * 256 + (long)q * 32;
    for (int r = wv; r < 32; r += 4) {
        const long rg = rbase + r;
        if (rg < N) {
            const float a0 = acc[r * DD + lane * 2];
            const float a1 = acc[r * DD + lane * 2 + 1];
            const unsigned int pk = ((unsigned int)f2bf(a1) << 16) | f2bf(a0);
            *(unsigned int*)(agg + rg * DD + lane * 2) = pk;
        }
    }
}

// ---------------- gru8: gates + GRU + out = h_new@W_out^T + b_out ----------------
__global__ __launch_bounds__(256) void gru8(
    const unsigned short* __restrict__ agg, const unsigned short* __restrict__ hbf,
    const unsigned short* __restrict__ Wih, const unsigned short* __restrict__ Whh,
    const unsigned short* __restrict__ Wo,
    const float* __restrict__ b_ih, const float* __restrict__ b_hh,
    const float* __restrict__ b_out, float* __restrict__ out, int M)
{
    __shared__ float4 WA[2048];
    __shared__ float4 WB[2048];
    const int tid = threadIdx.x;
    const int lane = tid & 63;
    const int w = tid >> 6;
    const int c15 = lane & 15;
    const int hi = lane >> 4;
    const long base = (long)blockIdx.x * 64;
    long arow = base + w * 16 + c15;
    if (arow >= M) arow = M - 1;

    f32x4 acc[8];
    float rg[32], zg[32];

    // ---- gate r ----
    stageW(WA, Wih, tid);
    stageW(WB, Whh, tid);
    __syncthreads();
#pragma unroll
    for (int ct = 0; ct < 8; ++ct) acc[ct] = (f32x4){0.f, 0.f, 0.f, 0.f};
#pragma unroll 1
    for (int s = 0; s < 4; ++s) {
        bf16x8 ai = fragG(agg, arow, s * 32 + 8 * hi);
        bf16x8 ah = fragG(hbf, arow, s * 32 + 8 * hi);
#pragma unroll
        for (int ct = 0; ct < 8; ++ct) {
            acc[ct] = MFMA16(ai, fragL(WA, lane, s, ct * 16 + c15), acc[ct]);
            acc[ct] = MFMA16(ah, fragL(WB, lane, s, ct * 16 + c15), acc[ct]);
        }
    }
#pragma unroll
    for (int ct = 0; ct < 8; ++ct)
#pragma unroll
        for (int j = 0; j < 4; ++j) {
            int c = ct * 16 + c15;
            float v = acc[ct][j] + b_ih[c] + b_hh[c];
            rg[ct * 4 + j] = 1.f / (1.f + __expf(-v));
        }
    __syncthreads();

    // ---- gate z ----
    stageW(WA, Wih + 16384, tid);
    stageW(WB, Whh + 16384, tid);
    __syncthreads();
#pragma unroll
    for (int ct = 0; ct < 8; ++ct) acc[ct] = (f32x4){0.f, 0.f, 0.f, 0.f};
#pragma unroll 1
    for (int s = 0; s < 4; ++s) {
        bf16x8 ai = fragG(agg, arow, s * 32 + 8 * hi);
        bf16x8 ah = fragG(hbf, arow, s * 32 + 8 * hi);
#pragma unroll
        for (int ct = 0; ct < 8; ++ct) {
            acc[ct] = MFMA16(ai, fragL(WA, lane, s, ct * 16 + c15), acc[ct]);
            acc[ct] = MFMA16(ah, fragL(WB, lane, s, ct * 16 + c15), acc[ct]);
        }
    }
#pragma unroll
    for (int ct = 0; ct < 8; ++ct)
#pragma unroll
        for (int j = 0; j < 4; ++j) {
            int c = ct * 16 + c15;
            float v = acc[ct][j] + b_ih[DD + c] + b_hh[DD + c];
            zg[ct * 4 + j] = 1.f / (1.f + __expf(-v));
        }
    __syncthreads();

    // ---- gate n ----
    stageW(WA, Wih + 32768, tid);
    stageW(WB, Whh + 32768, tid);
    __syncthreads();
    f32x4 acch[8];
#pragma unroll
    for (int ct = 0; ct < 8; ++ct) {
        acc[ct] = (f32x4){0.f, 0.f, 0.f, 0.f};
        acch[ct] = (f32x4){0.f, 0.f, 0.f, 0.f};
    }
#pragma unroll 1
    for (int s = 0; s < 4; ++s) {
        bf16x8 ai = fragG(agg, arow, s * 32 + 8 * hi);
        bf16x8 ah = fragG(hbf, arow, s * 32 + 8 * hi);
#pragma unroll
        for (int ct = 0; ct < 8; ++ct) {
            acc[ct]  = MFMA16(ai, fragL(WA, lane, s, ct * 16 + c15), acc[ct]);
            acch[ct] = MFMA16(ah, fragL(WB, lane, s, ct * 16 + c15), acch[ct]);
        }
    }
    __syncthreads();

    // ---- GRU combine; h_new -> LDS (overlay WA); stage W_out -> WB ----
    unsigned short* Hu = reinterpret_cast<unsigned short*>(WA);
#pragma unroll
    for (int ct = 0; ct < 8; ++ct)
#pragma unroll
        for (int j = 0; j < 4; ++j) {
            int c = ct * 16 + c15;
            int rloc = w * 16 + 4 * hi + j;
            long r = base + rloc;
            long rr = (r < M) ? r : (M - 1);
            float inb = acc[ct][j] + b_ih[2 * DD + c];
            float hnb = acch[ct][j] + b_hh[2 * DD + c];
            float n = tanhf(inb + rg[ct * 4 + j] * hnb);
            float hv = bf2f(hbf[rr * DD + c]);
            float z = zg[ct * 4 + j];
            float hnew = (1.f - z) * n + z * hv;
            Hu[rloc * DD + ((c >> 3) ^ (rloc & 15)) * 8 + (c & 7)] = f2bf(hnew);
        }
    stageW(WB, Wo, tid);
    __syncthreads();

    // ---- out = h_new @ W_out^T + b_out ----
#pragma unroll
    for (int ct = 0; ct < 8; ++ct) acc[ct] = (f32x4){0.f, 0.f, 0.f, 0.f};
#pragma unroll 1
    for (int s = 0; s < 4; ++s) {
        bf16x8 a = fragL(WA, lane, s, w * 16 + c15);
#pragma unroll
        for (int ct = 0; ct < 8; ++ct)
            acc[ct] = MFMA16(a, fragL(WB, lane, s, ct * 16 + c15), acc[ct]);
    }
#pragma unroll
    for (int ct = 0; ct < 8; ++ct)
#pragma unroll
        for (int j = 0; j < 4; ++j) {
            long r = base + w * 16 + 4 * hi + j;
            if (r < M) out[r * DD + ct * 16 + c15] = acc[ct][j] + b_out[ct * 16 + c15];
        }
}

extern "C" void kernel_launch(void* const* d_in, const int* in_sizes, int n_in,
                              void* d_out, int out_size, void* d_ws, size_t ws_size,
                              hipStream_t stream) {
    const float* x     = (const float*)d_in[0];
    const int*   ei    = (const int*)d_in[1];
    const float* W_in  = (const float*)d_in[2];
    const float* b_in  = (const float*)d_in[3];
    const float* W_msg = (const float*)d_in[4];
    const float* W_ih  = (const float*)d_in[5];
    const float* b_ih  = (const float*)d_in[6];
    const float* W_hh  = (const float*)d_in[7];
    const float* b_hh  = (const float*)d_in[8];
    const float* W_out = (const float*)d_in[9];
    const float* b_out = (const float*)d_in[10];

    const int N = in_sizes[0] / DD;     // 100000
    const int E = in_sizes[1] / 2;      // 1600000
    float* out = (float*)d_out;

    // ws: [0, 512KB) weights bf16 | h_bf | m_bf | agg_bf  (each 25.6MB)
    const size_t slotE = (size_t)N * DD;
    unsigned short* wb     = (unsigned short*)d_ws;
    unsigned short* h_bf   = (unsigned short*)((char*)d_ws + (1 << 19));
    unsigned short* m_bf   = h_bf + slotE;
    unsigned short* agg_bf = m_bf + slotE;

    // bin scratch in d_out (dead until gru8 writes out at the very end)
    const int nbc = (N + 255) >> 8;     // 391
    unsigned int* bucket = (unsigned int*)d_out;
    int* gcur = (int*)((char*)d_out + (16u << 20));
    int* govf = gcur + 512;
    unsigned long long* ovf = (unsigned long long*)(gcur + 1024);

    dim3 blk(256);
    const int gblocks = (N + 63) / 64;   // 1563

    wconv<<<(148480 + 255) / 256, blk, 0, stream>>>(W_in, W_msg, W_ih, W_hh, W_out, wb, gcur);
    front<<<NBIN_BLOCKS + gblocks, blk, 0, stream>>>(ei, E, nbc, bucket, gcur, govf, ovf,
                                                     x, wb, wb + 16384, b_in, h_bf, m_bf, N);
    bin_reduce<<<nbc * 8, blk, 0, stream>>>(m_bf, bucket, gcur, govf, ovf, agg_bf, N);
    gru8<<<gblocks, blk, 0, stream>>>(agg_bf, h_bf, wb + 32768, wb + 81920, wb + 131072,
                                      b_ih, b_hh, b_out, out, N);
}